// Round 1
// baseline (1407.249 us; speedup 1.0000x reference)
//
#include <hip/hip_runtime.h>

// SimpleMTP: 3 sequential MTP heads on MI355X.
// All heavy math in f16 MFMA (16x16x32, f32 accum); residual/norms in f32.
// Workspace layout (~170 MB): f16 copies of embed + weights, padded (2048-row)
// activation buffers so 128-tile GEMM staging never reads OOB.

#define NPOS   509
#define MROWS  2036   // 4*509 valid rows
#define MPAD   2048   // padded to 16 * 128-row tiles
#define DMODEL 1024

typedef _Float16 f16;
typedef _Float16 f16x8 __attribute__((ext_vector_type(8)));
typedef _Float16 f16x4 __attribute__((ext_vector_type(4)));
typedef float    f32x4 __attribute__((ext_vector_type(4)));

// ---------------- async global->LDS (width 16) ----------------
__device__ __forceinline__ void gld_lds16(const void* g, void* l) {
  __builtin_amdgcn_global_load_lds(
      (const __attribute__((address_space(1))) void*)g,
      (__attribute__((address_space(3))) void*)l, 16, 0, 0);
}

// ---------------- f32 -> f16 convert (8 elems/thread) ----------------
__global__ __launch_bounds__(256) void conv_f32_f16(const float* __restrict__ src,
                                                    f16* __restrict__ dst, long n) {
  long i = ((long)blockIdx.x * 256 + threadIdx.x) * 8;
  if (i + 8 <= n) {
    float4 a = *(const float4*)(src + i);
    float4 b = *(const float4*)(src + i + 4);
    f16x8 o = {(f16)a.x, (f16)a.y, (f16)a.z, (f16)a.w,
               (f16)b.x, (f16)b.y, (f16)b.z, (f16)b.w};
    *(f16x8*)(dst + i) = o;
  }
}

// ---------------- gather h_prev(0) = embed[token_ids[b, t]] ----------------
__global__ __launch_bounds__(256) void gather_h0(const float* __restrict__ embed,
                                                 const int* __restrict__ tok,
                                                 float* __restrict__ hprev) {
  int r = blockIdx.x;
  int b = r / NPOS, t = r - b * NPOS;
  const float4* src = (const float4*)(embed + (long)tok[b * 512 + t] * DMODEL);
  float4* dst = (float4*)(hprev + (long)r * DMODEL);
  dst[threadIdx.x] = src[threadIdx.x];
}

// ---------------- block reduction of a float pair (256 threads) ----------------
__device__ __forceinline__ float2 block_reduce2(float a, float b) {
  #pragma unroll
  for (int off = 32; off > 0; off >>= 1) {
    a += __shfl_xor(a, off);
    b += __shfl_xor(b, off);
  }
  __shared__ float2 red[4];
  int wv = threadIdx.x >> 6;
  if ((threadIdx.x & 63) == 0) red[wv] = make_float2(a, b);
  __syncthreads();
  float2 r0 = red[0], r1 = red[1], r2 = red[2], r3 = red[3];
  return make_float2(r0.x + r1.x + r2.x + r3.x, r0.y + r1.y + r2.y + r3.y);
}

// ---------------- merged = [rmsnorm(h_prev), rmsnorm(tok)] in f16 ----------------
__global__ __launch_bounds__(256) void merge_rms(const float* __restrict__ hprev,
                                                 const float* __restrict__ embed,
                                                 const int* __restrict__ tok,
                                                 f16* __restrict__ merged, int koff) {
  int r = blockIdx.x;
  int b = r / NPOS, t = r - b * NPOS;
  int tid = threadIdx.x;
  float4 hv = ((const float4*)(hprev + (long)r * DMODEL))[tid];
  float4 tv = ((const float4*)(embed + (long)tok[b * 512 + t + koff] * DMODEL))[tid];
  float sh = hv.x * hv.x + hv.y * hv.y + hv.z * hv.z + hv.w * hv.w;
  float st = tv.x * tv.x + tv.y * tv.y + tv.z * tv.z + tv.w * tv.w;
  float2 tot = block_reduce2(sh, st);
  float ih = 1.0f / sqrtf(tot.x * (1.0f / DMODEL) + 1e-8f);
  float it = 1.0f / sqrtf(tot.y * (1.0f / DMODEL) + 1e-8f);
  f16x4 oh = {(f16)(hv.x * ih), (f16)(hv.y * ih), (f16)(hv.z * ih), (f16)(hv.w * ih)};
  f16x4 ot = {(f16)(tv.x * it), (f16)(tv.y * it), (f16)(tv.z * it), (f16)(tv.w * it)};
  *(f16x4*)(merged + (long)r * 2048 + tid * 4) = oh;
  *(f16x4*)(merged + (long)r * 2048 + 1024 + tid * 4) = ot;
}

// ---------------- y = LN(x + res) * g + b -> (f32, f16) ----------------
__global__ __launch_bounds__(256) void add_ln(const float* __restrict__ x,
                                              const float* __restrict__ res,
                                              const float* __restrict__ g,
                                              const float* __restrict__ bb,
                                              float* __restrict__ yf,
                                              f16* __restrict__ yh) {
  int r = blockIdx.x, tid = threadIdx.x;
  float4 a = ((const float4*)(x + (long)r * DMODEL))[tid];
  float4 c = ((const float4*)(res + (long)r * DMODEL))[tid];
  a.x += c.x; a.y += c.y; a.z += c.z; a.w += c.w;
  float s  = a.x + a.y + a.z + a.w;
  float ss = a.x * a.x + a.y * a.y + a.z * a.z + a.w * a.w;
  float2 tot = block_reduce2(s, ss);
  float mean = tot.x * (1.0f / DMODEL);
  float var  = tot.y * (1.0f / DMODEL) - mean * mean;
  float inv  = 1.0f / sqrtf(var + 1e-5f);
  float4 gv = ((const float4*)g)[tid];
  float4 bv = ((const float4*)bb)[tid];
  float y0 = (a.x - mean) * inv * gv.x + bv.x;
  float y1 = (a.y - mean) * inv * gv.y + bv.y;
  float y2 = (a.z - mean) * inv * gv.z + bv.z;
  float y3 = (a.w - mean) * inv * gv.w + bv.w;
  float4 o = {y0, y1, y2, y3};
  ((float4*)(yf + (long)r * DMODEL))[tid] = o;
  f16x4 oh = {(f16)y0, (f16)y1, (f16)y2, (f16)y3};
  *(f16x4*)(yh + (long)r * DMODEL + tid * 4) = oh;
}

// ---------------- GEMM: C[M,N] = A[M,K] @ B[N,K]^T (+bias) ----------------
// 128x128 tile, 4 waves (2x2), 16x16x32 f16 MFMA, global_load_lds staging.
// m97 2-barrier structure. A rows must be readable up to gridDim.y*128 (padded).
template <int HAS_BIAS, int RELU, int WF32, int WF16, int MASK>
__global__ __launch_bounds__(256) void gemm_bt(const f16* __restrict__ A,
                                               const f16* __restrict__ B,
                                               const float* __restrict__ bias,
                                               float* __restrict__ Cf,
                                               f16* __restrict__ Ch,
                                               int K, int N, long ldc, long coff,
                                               int mval) {
  __shared__ __align__(16) f16 sA[128 * 32];
  __shared__ __align__(16) f16 sB[128 * 32];
  const int tid  = threadIdx.x;
  const int lane = tid & 63, wv = tid >> 6;
  const int wm = wv >> 1, wn = wv & 1;
  const int bm = blockIdx.y, bn = blockIdx.x;

  // staging: chunk c covers sA[c*8 .. c*8+8) == row c/4, cols (c%4)*8..+8
  const f16* gA0 = A + ((long)(bm * 128 + (tid >> 2))) * K + (tid & 3) * 8;
  const f16* gA1 = A + ((long)(bm * 128 + 64 + (tid >> 2))) * K + (tid & 3) * 8;
  const f16* gB0 = B + ((long)(bn * 128 + (tid >> 2))) * K + (tid & 3) * 8;
  const f16* gB1 = B + ((long)(bn * 128 + 64 + (tid >> 2))) * K + (tid & 3) * 8;
  f16* lA0 = sA + tid * 8;
  f16* lA1 = sA + (tid + 256) * 8;
  f16* lB0 = sB + tid * 8;
  f16* lB1 = sB + (tid + 256) * 8;

  f32x4 acc[4][4] = {};
  const int lr = lane & 15, lk = lane >> 4;
  const int aoff = (wm * 64 + lr) * 32 + lk * 8;  // + fm*16*32
  const int boff = (wn * 64 + lr) * 32 + lk * 8;  // + fn*16*32

  const int nk = K >> 5;
  for (int kt = 0; kt < nk; ++kt) {
    __syncthreads();  // prior iteration's ds_reads done before overwrite
    gld_lds16(gA0, lA0);
    gld_lds16(gA1, lA1);
    gld_lds16(gB0, lB0);
    gld_lds16(gB1, lB1);
    gA0 += 32; gA1 += 32; gB0 += 32; gB1 += 32;
    __syncthreads();  // drains vmcnt -> staged data visible

    f16x8 af[4], bf[4];
    #pragma unroll
    for (int i = 0; i < 4; ++i) {
      af[i] = *(const f16x8*)&sA[aoff + i * 512];
      bf[i] = *(const f16x8*)&sB[boff + i * 512];
    }
    #pragma unroll
    for (int i = 0; i < 4; ++i)
      #pragma unroll
      for (int j = 0; j < 4; ++j)
        acc[i][j] = __builtin_amdgcn_mfma_f32_16x16x32_f16(af[i], bf[j], acc[i][j], 0, 0, 0);
  }

  // epilogue: C/D layout col=lane&15, row=(lane>>4)*4+reg
  const int row0 = bm * 128 + wm * 64 + lk * 4;
  const int col0 = bn * 128 + wn * 64 + lr;
  #pragma unroll
  for (int i = 0; i < 4; ++i) {
    #pragma unroll
    for (int j = 0; j < 4; ++j) {
      int col = col0 + j * 16;
      float bs = HAS_BIAS ? bias[col] : 0.0f;
      #pragma unroll
      for (int rg = 0; rg < 4; ++rg) {
        int row = row0 + i * 16 + rg;
        if (!MASK || row < mval) {
          float v = acc[i][j][rg] + bs;
          if (RELU) v = v > 0.0f ? v : 0.0f;
          if (WF32) Cf[(long)row * ldc + coff + col] = v;
          if (WF16) Ch[(long)row * N + col] = (f16)v;
        }
      }
    }
  }
}

// ---------------- host-side orchestration ----------------
extern "C" void kernel_launch(void* const* d_in, const int* in_sizes, int n_in,
                              void* d_out, int out_size, void* d_ws, size_t ws_size,
                              hipStream_t stream) {
  const int*   tok   = (const int*)d_in[0];
  const float* embed = (const float*)d_in[1];
  auto P = [&](int k, int j) { return (const float*)d_in[2 + k * 14 + j]; };
  float* out = (float*)d_out;

  char* w = (char*)d_ws;
  auto alloc = [&](size_t bytes) { char* p = w; w += bytes; return p; };

  f16* embed_h = (f16*)alloc((size_t)32000 * 1024 * 2);
  f16 *Wm_h[3], *Wv_h[3], *Wo_h[3], *W1_h[3], *W2_h[3];
  for (int k = 0; k < 3; ++k) {
    Wm_h[k] = (f16*)alloc((size_t)1024 * 2048 * 2);
    Wv_h[k] = (f16*)alloc((size_t)1024 * 1024 * 2);
    Wo_h[k] = (f16*)alloc((size_t)1024 * 1024 * 2);
    W1_h[k] = (f16*)alloc((size_t)2048 * 1024 * 2);
    W2_h[k] = (f16*)alloc((size_t)1024 * 2048 * 2);
  }
  float* hprev  = (float*)alloc((size_t)MPAD * 1024 * 4);
  f16*   h_h    = (f16*)alloc((size_t)MPAD * 1024 * 2);
  f16*   merged = (f16*)alloc((size_t)MPAD * 2048 * 2);
  float* xf     = (float*)alloc((size_t)MPAD * 1024 * 4);
  f16*   xh     = (f16*)alloc((size_t)MPAD * 1024 * 2);
  f16*   vh     = (f16*)alloc((size_t)MPAD * 1024 * 2);
  f16*   ff1    = (f16*)alloc((size_t)MPAD * 2048 * 2);
  float* t1     = (float*)alloc((size_t)MPAD * 1024 * 4);

  // weight/embed conversion to f16 (each call; deterministic)
  conv_f32_f16<<<16000, 256, 0, stream>>>(embed, embed_h, (long)32000 * 1024);
  for (int k = 0; k < 3; ++k) {
    conv_f32_f16<<<1024, 256, 0, stream>>>(P(k, 0), Wm_h[k], (long)1024 * 2048);
    conv_f32_f16<<<512,  256, 0, stream>>>(P(k, 2), Wv_h[k], (long)1024 * 1024);
    conv_f32_f16<<<512,  256, 0, stream>>>(P(k, 4), Wo_h[k], (long)1024 * 1024);
    conv_f32_f16<<<1024, 256, 0, stream>>>(P(k, 6), W1_h[k], (long)2048 * 1024);
    conv_f32_f16<<<1024, 256, 0, stream>>>(P(k, 8), W2_h[k], (long)1024 * 2048);
  }
  gather_h0<<<MROWS, 256, 0, stream>>>(embed, tok, hprev);

  for (int k = 0; k < 3; ++k) {
    merge_rms<<<MROWS, 256, 0, stream>>>(hprev, embed, tok, merged, k + 1);
    // x = merged @ Wmerge^T + bmerge  (f32 + f16)
    gemm_bt<1, 0, 1, 1, 0><<<dim3(8, 16), 256, 0, stream>>>(
        merged, Wm_h[k], P(k, 1), xf, xh, 2048, 1024, 1024L, 0L, MROWS);
    // v = x @ Wv^T + bv (f16)
    gemm_bt<1, 0, 0, 1, 0><<<dim3(8, 16), 256, 0, stream>>>(
        xh, Wv_h[k], P(k, 3), nullptr, vh, 1024, 1024, 1024L, 0L, MROWS);
    // attn = v @ Wo^T + bo (f32)
    gemm_bt<1, 0, 1, 0, 0><<<dim3(8, 16), 256, 0, stream>>>(
        vh, Wo_h[k], P(k, 5), t1, nullptr, 1024, 1024, 1024L, 0L, MROWS);
    // x = LN(x + attn)
    add_ln<<<MROWS, 256, 0, stream>>>(xf, t1, P(k, 10), P(k, 11), xf, xh);
    // ff1 = relu(x @ W1^T + b1) (f16)
    gemm_bt<1, 1, 0, 1, 0><<<dim3(16, 16), 256, 0, stream>>>(
        xh, W1_h[k], P(k, 7), nullptr, ff1, 1024, 2048, 2048L, 0L, MROWS);
    // ff = ff1 @ W2^T + b2 (f32)
    gemm_bt<1, 0, 1, 0, 0><<<dim3(8, 16), 256, 0, stream>>>(
        ff1, W2_h[k], P(k, 9), t1, nullptr, 2048, 1024, 1024L, 0L, MROWS);
    // h = LN(x + ff) -> hprev (next layer), h_h (f16)
    add_ln<<<MROWS, 256, 0, stream>>>(xf, t1, P(k, 12), P(k, 13), hprev, h_h);
    // logits = h @ embed^T, strided into out[:, :, k, :], masked to 2036 rows
    gemm_bt<0, 0, 1, 0, 1><<<dim3(250, 16), 256, 0, stream>>>(
        h_h, embed_h, nullptr, out, nullptr, 1024, 32000, 96000L,
        (long)k * 32000, MROWS);
  }
}

// Round 2
// 1359.103 us; speedup vs baseline: 1.0354x; 1.0354x over previous
//
#include <hip/hip_runtime.h>

// SimpleMTP: 3 sequential MTP heads on MI355X.
// f16 MFMA everywhere heavy; f32 residual/norms.
// Logits GEMM: 256x256 8-phase counted-vmcnt schedule (T2..T5 stack).
// Small GEMMs: m97 128x128 2-barrier structure.

#define NPOS   509
#define MROWS  2036
#define MPAD   2048
#define DMODEL 1024

typedef _Float16 f16;
typedef _Float16 f16x8 __attribute__((ext_vector_type(8)));
typedef _Float16 f16x4 __attribute__((ext_vector_type(4)));
typedef float    f32x4 __attribute__((ext_vector_type(4)));

#define MFMA16(a, b, c) __builtin_amdgcn_mfma_f32_16x16x32_f16(a, b, c, 0, 0, 0)

__device__ __forceinline__ void gld_lds16(const void* g, void* l) {
  __builtin_amdgcn_global_load_lds(
      (const __attribute__((address_space(1))) void*)g,
      (__attribute__((address_space(3))) void*)l, 16, 0, 0);
}

// ---------------- f32 -> f16 convert ----------------
__global__ __launch_bounds__(256) void conv_f32_f16(const float* __restrict__ src,
                                                    f16* __restrict__ dst, long n) {
  long i = ((long)blockIdx.x * 256 + threadIdx.x) * 8;
  if (i + 8 <= n) {
    float4 a = *(const float4*)(src + i);
    float4 b = *(const float4*)(src + i + 4);
    f16x8 o = {(f16)a.x, (f16)a.y, (f16)a.z, (f16)a.w,
               (f16)b.x, (f16)b.y, (f16)b.z, (f16)b.w};
    *(f16x8*)(dst + i) = o;
  }
}

// ---------------- gather h_prev(0) ----------------
__global__ __launch_bounds__(256) void gather_h0(const float* __restrict__ embed,
                                                 const int* __restrict__ tok,
                                                 float* __restrict__ hprev) {
  int r = blockIdx.x;
  int b = r / NPOS, t = r - b * NPOS;
  const float4* src = (const float4*)(embed + (long)tok[b * 512 + t] * DMODEL);
  float4* dst = (float4*)(hprev + (long)r * DMODEL);
  dst[threadIdx.x] = src[threadIdx.x];
}

__device__ __forceinline__ float2 block_reduce2(float a, float b) {
  #pragma unroll
  for (int off = 32; off > 0; off >>= 1) {
    a += __shfl_xor(a, off);
    b += __shfl_xor(b, off);
  }
  __shared__ float2 red[4];
  int wv = threadIdx.x >> 6;
  if ((threadIdx.x & 63) == 0) red[wv] = make_float2(a, b);
  __syncthreads();
  float2 r0 = red[0], r1 = red[1], r2 = red[2], r3 = red[3];
  return make_float2(r0.x + r1.x + r2.x + r3.x, r0.y + r1.y + r2.y + r3.y);
}

// ---------------- merged = [rmsnorm(h_prev), rmsnorm(tok)] ----------------
__global__ __launch_bounds__(256) void merge_rms(const float* __restrict__ hprev,
                                                 const float* __restrict__ embed,
                                                 const int* __restrict__ tok,
                                                 f16* __restrict__ merged, int koff) {
  int r = blockIdx.x;
  int b = r / NPOS, t = r - b * NPOS;
  int tid = threadIdx.x;
  float4 hv = ((const float4*)(hprev + (long)r * DMODEL))[tid];
  float4 tv = ((const float4*)(embed + (long)tok[b * 512 + t + koff] * DMODEL))[tid];
  float sh = hv.x * hv.x + hv.y * hv.y + hv.z * hv.z + hv.w * hv.w;
  float st = tv.x * tv.x + tv.y * tv.y + tv.z * tv.z + tv.w * tv.w;
  float2 tot = block_reduce2(sh, st);
  float ih = 1.0f / sqrtf(tot.x * (1.0f / DMODEL) + 1e-8f);
  float it = 1.0f / sqrtf(tot.y * (1.0f / DMODEL) + 1e-8f);
  f16x4 oh = {(f16)(hv.x * ih), (f16)(hv.y * ih), (f16)(hv.z * ih), (f16)(hv.w * ih)};
  f16x4 ot = {(f16)(tv.x * it), (f16)(tv.y * it), (f16)(tv.z * it), (f16)(tv.w * it)};
  *(f16x4*)(merged + (long)r * 2048 + tid * 4) = oh;
  *(f16x4*)(merged + (long)r * 2048 + 1024 + tid * 4) = ot;
}

// ---------------- y = LN(x + res) * g + b ----------------
__global__ __launch_bounds__(256) void add_ln(const float* __restrict__ x,
                                              const float* __restrict__ res,
                                              const float* __restrict__ g,
                                              const float* __restrict__ bb,
                                              float* __restrict__ yf,
                                              f16* __restrict__ yh) {
  int r = blockIdx.x, tid = threadIdx.x;
  float4 a = ((const float4*)(x + (long)r * DMODEL))[tid];
  float4 c = ((const float4*)(res + (long)r * DMODEL))[tid];
  a.x += c.x; a.y += c.y; a.z += c.z; a.w += c.w;
  float s  = a.x + a.y + a.z + a.w;
  float ss = a.x * a.x + a.y * a.y + a.z * a.z + a.w * a.w;
  float2 tot = block_reduce2(s, ss);
  float mean = tot.x * (1.0f / DMODEL);
  float var  = tot.y * (1.0f / DMODEL) - mean * mean;
  float inv  = 1.0f / sqrtf(var + 1e-5f);
  float4 gv = ((const float4*)g)[tid];
  float4 bv = ((const float4*)bb)[tid];
  float y0 = (a.x - mean) * inv * gv.x + bv.x;
  float y1 = (a.y - mean) * inv * gv.y + bv.y;
  float y2 = (a.z - mean) * inv * gv.z + bv.z;
  float y3 = (a.w - mean) * inv * gv.w + bv.w;
  float4 o = {y0, y1, y2, y3};
  ((float4*)(yf + (long)r * DMODEL))[tid] = o;
  f16x4 oh = {(f16)y0, (f16)y1, (f16)y2, (f16)y3};
  *(f16x4*)(yh + (long)r * DMODEL + tid * 4) = oh;
}

// ---------------- small GEMM: 128x128 m97 structure ----------------
template <int HAS_BIAS, int RELU, int WF32, int WF16, int MASK>
__global__ __launch_bounds__(256) void gemm_bt(const f16* __restrict__ A,
                                               const f16* __restrict__ B,
                                               const float* __restrict__ bias,
                                               float* __restrict__ Cf,
                                               f16* __restrict__ Ch,
                                               int K, int N, long ldc, long coff,
                                               int mval) {
  __shared__ __align__(16) f16 sA[128 * 32];
  __shared__ __align__(16) f16 sB[128 * 32];
  const int tid  = threadIdx.x;
  const int lane = tid & 63, wv = tid >> 6;
  const int wm = wv >> 1, wn = wv & 1;
  const int bm = blockIdx.y, bn = blockIdx.x;

  const f16* gA0 = A + ((long)(bm * 128 + (tid >> 2))) * K + (tid & 3) * 8;
  const f16* gA1 = A + ((long)(bm * 128 + 64 + (tid >> 2))) * K + (tid & 3) * 8;
  const f16* gB0 = B + ((long)(bn * 128 + (tid >> 2))) * K + (tid & 3) * 8;
  const f16* gB1 = B + ((long)(bn * 128 + 64 + (tid >> 2))) * K + (tid & 3) * 8;
  f16* lA0 = sA + tid * 8;
  f16* lA1 = sA + (tid + 256) * 8;
  f16* lB0 = sB + tid * 8;
  f16* lB1 = sB + (tid + 256) * 8;

  f32x4 acc[4][4] = {};
  const int lr = lane & 15, lk = lane >> 4;
  const int aoff = (wm * 64 + lr) * 32 + lk * 8;
  const int boff = (wn * 64 + lr) * 32 + lk * 8;

  const int nk = K >> 5;
  for (int kt = 0; kt < nk; ++kt) {
    __syncthreads();
    gld_lds16(gA0, lA0);
    gld_lds16(gA1, lA1);
    gld_lds16(gB0, lB0);
    gld_lds16(gB1, lB1);
    gA0 += 32; gA1 += 32; gB0 += 32; gB1 += 32;
    __syncthreads();

    f16x8 af[4], bf[4];
    #pragma unroll
    for (int i = 0; i < 4; ++i) {
      af[i] = *(const f16x8*)&sA[aoff + i * 512];
      bf[i] = *(const f16x8*)&sB[boff + i * 512];
    }
    #pragma unroll
    for (int i = 0; i < 4; ++i)
      #pragma unroll
      for (int j = 0; j < 4; ++j)
        acc[i][j] = MFMA16(af[i], bf[j], acc[i][j]);
  }

  const int row0 = bm * 128 + wm * 64 + lk * 4;
  const int col0 = bn * 128 + wn * 64 + lr;
  #pragma unroll
  for (int i = 0; i < 4; ++i) {
    #pragma unroll
    for (int j = 0; j < 4; ++j) {
      int col = col0 + j * 16;
      float bs = HAS_BIAS ? bias[col] : 0.0f;
      #pragma unroll
      for (int rg = 0; rg < 4; ++rg) {
        int row = row0 + i * 16 + rg;
        if (!MASK || row < mval) {
          float v = acc[i][j][rg] + bs;
          if (RELU) v = v > 0.0f ? v : 0.0f;
          if (WF32) Cf[(long)row * ldc + coff + col] = v;
          if (WF16) Ch[(long)row * N + col] = (f16)v;
        }
      }
    }
  }
}

// ---------------- logits GEMM: 256x256, BK=64, 8-phase counted vmcnt ----------------
// 8 waves (2M x 4N), wave tile 128x64. LDS: [op][dbuf][khalf][256x32 f16] = 128 KiB.
// Stage order per iter (tile t+1): Ak0,Bk0,Ak1,Bk1; 2 loads each.
// Ledger: entering ph1 <=8 in flight; +2 -> 10; need oldest 4 -> vmcnt(6). Same ph3.
__global__ __launch_bounds__(512, 2) void gemm256(const f16* __restrict__ A,
                                                  const f16* __restrict__ B,
                                                  float* __restrict__ C,
                                                  int K, long ldc, long coff,
                                                  int mval) {
  __shared__ __align__(16) f16 sA[2][2][8192];
  __shared__ __align__(16) f16 sB[2][2][8192];
  const int tid = threadIdx.x;
  const int lane = tid & 63;
  const int wv = tid >> 6;
  const int wm = wv >> 2, wn = wv & 3;
  const int lr = lane & 15, lk = lane >> 4;
  const int bn = blockIdx.x, bm = blockIdx.y;

  const int srow = tid >> 2;          // 0..127
  const int scol = (tid & 3) * 8;     // f16 col within k-half
  const f16* gA = A + (long)(bm * 256 + srow) * K + scol;
  const f16* gB = B + (long)(bn * 256 + srow) * K + scol;
  const long rstep = 128L * (long)K;

  const int aoff = (wm * 128 + lr) * 32 + lk * 8;  // + mi*512
  const int boff = (wn * 64  + lr) * 32 + lk * 8;  // + ni*512

  f32x4 acc[8][4] = {};

#define STAGE_A(buf, h, ko)                                        \
  gld_lds16(gA + (ko) + (h) * 32, &sA[buf][h][tid * 8]);           \
  gld_lds16(gA + (ko) + (h) * 32 + rstep, &sA[buf][h][tid * 8 + 4096]);
#define STAGE_B(buf, h, ko)                                        \
  gld_lds16(gB + (ko) + (h) * 32, &sB[buf][h][tid * 8]);           \
  gld_lds16(gB + (ko) + (h) * 32 + rstep, &sB[buf][h][tid * 8 + 4096]);
#define BARRIER asm volatile("s_barrier" ::: "memory")
#define VMCNT6  asm volatile("s_waitcnt vmcnt(6)" ::: "memory")

  // prologue: tile 0 into buf 0 (order Ak0,Bk0,Ak1,Bk1)
  STAGE_A(0, 0, 0); STAGE_B(0, 0, 0); STAGE_A(0, 1, 0); STAGE_B(0, 1, 0);

  const int nt = K >> 6;
  for (int t = 0; t < nt; ++t) {
    const int cur = t & 1, nxt = cur ^ 1;
    const long kn = (long)((t + 1 < nt) ? (t + 1) : 0) * 64;  // wrap keeps ledger uniform
    f16x8 af[8], bf[4];

    // phase 1: ksub0, n-frags 0-1
    STAGE_A(nxt, 0, kn);
    VMCNT6;
    BARRIER;
    #pragma unroll
    for (int mi = 0; mi < 8; ++mi) af[mi] = *(const f16x8*)&sA[cur][0][aoff + mi * 512];
    bf[0] = *(const f16x8*)&sB[cur][0][boff];
    bf[1] = *(const f16x8*)&sB[cur][0][boff + 512];
    __builtin_amdgcn_s_setprio(1);
    #pragma unroll
    for (int mi = 0; mi < 8; ++mi) {
      acc[mi][0] = MFMA16(af[mi], bf[0], acc[mi][0]);
      acc[mi][1] = MFMA16(af[mi], bf[1], acc[mi][1]);
    }
    __builtin_amdgcn_s_setprio(0);
    BARRIER;

    // phase 2: ksub0, n-frags 2-3 (af reused)
    STAGE_B(nxt, 0, kn);
    BARRIER;
    bf[2] = *(const f16x8*)&sB[cur][0][boff + 1024];
    bf[3] = *(const f16x8*)&sB[cur][0][boff + 1536];
    __builtin_amdgcn_s_setprio(1);
    #pragma unroll
    for (int mi = 0; mi < 8; ++mi) {
      acc[mi][2] = MFMA16(af[mi], bf[2], acc[mi][2]);
      acc[mi][3] = MFMA16(af[mi], bf[3], acc[mi][3]);
    }
    __builtin_amdgcn_s_setprio(0);
    BARRIER;

    // phase 3: ksub1, n-frags 0-1
    STAGE_A(nxt, 1, kn);
    VMCNT6;
    BARRIER;
    #pragma unroll
    for (int mi = 0; mi < 8; ++mi) af[mi] = *(const f16x8*)&sA[cur][1][aoff + mi * 512];
    bf[0] = *(const f16x8*)&sB[cur][1][boff];
    bf[1] = *(const f16x8*)&sB[cur][1][boff + 512];
    __builtin_amdgcn_s_setprio(1);
    #pragma unroll
    for (int mi = 0; mi < 8; ++mi) {
      acc[mi][0] = MFMA16(af[mi], bf[0], acc[mi][0]);
      acc[mi][1] = MFMA16(af[mi], bf[1], acc[mi][1]);
    }
    __builtin_amdgcn_s_setprio(0);
    BARRIER;

    // phase 4: ksub1, n-frags 2-3
    STAGE_B(nxt, 1, kn);
    BARRIER;
    bf[2] = *(const f16x8*)&sB[cur][1][boff + 1024];
    bf[3] = *(const f16x8*)&sB[cur][1][boff + 1536];
    __builtin_amdgcn_s_setprio(1);
    #pragma unroll
    for (int mi = 0; mi < 8; ++mi) {
      acc[mi][2] = MFMA16(af[mi], bf[2], acc[mi][2]);
      acc[mi][3] = MFMA16(af[mi], bf[3], acc[mi][3]);
    }
    __builtin_amdgcn_s_setprio(0);
    BARRIER;
  }
  asm volatile("s_waitcnt vmcnt(0)" ::: "memory");  // drain dangling stages

  // epilogue: frag (mi,ni): row = base + mi*16 + lk*4 + rg, col = base + ni*16 + lr
  const int row0 = bm * 256 + wm * 128 + lk * 4;
  const int col0 = bn * 256 + wn * 64 + lr;
  #pragma unroll
  for (int mi = 0; mi < 8; ++mi) {
    #pragma unroll
    for (int ni = 0; ni < 4; ++ni) {
      int col = col0 + ni * 16;
      #pragma unroll
      for (int rg = 0; rg < 4; ++rg) {
        int row = row0 + mi * 16 + rg;
        if (row < mval) C[(long)row * ldc + coff + col] = acc[mi][ni][rg];
      }
    }
  }
#undef STAGE_A
#undef STAGE_B
#undef BARRIER
#undef VMCNT6
}

// ---------------- host-side orchestration ----------------
extern "C" void kernel_launch(void* const* d_in, const int* in_sizes, int n_in,
                              void* d_out, int out_size, void* d_ws, size_t ws_size,
                              hipStream_t stream) {
  const int*   tok   = (const int*)d_in[0];
  const float* embed = (const float*)d_in[1];
  auto P = [&](int k, int j) { return (const float*)d_in[2 + k * 14 + j]; };
  float* out = (float*)d_out;

  char* w = (char*)d_ws;
  auto alloc = [&](size_t bytes) { char* p = w; w += bytes; return p; };

  f16* embed_h = (f16*)alloc((size_t)32000 * 1024 * 2);
  f16 *Wm_h[3], *Wv_h[3], *Wo_h[3], *W1_h[3], *W2_h[3];
  for (int k = 0; k < 3; ++k) {
    Wm_h[k] = (f16*)alloc((size_t)1024 * 2048 * 2);
    Wv_h[k] = (f16*)alloc((size_t)1024 * 1024 * 2);
    Wo_h[k] = (f16*)alloc((size_t)1024 * 1024 * 2);
    W1_h[k] = (f16*)alloc((size_t)2048 * 1024 * 2);
    W2_h[k] = (f16*)alloc((size_t)1024 * 2048 * 2);
  }
  float* hprev  = (float*)alloc((size_t)MPAD * 1024 * 4);
  f16*   h_h    = (f16*)alloc((size_t)MPAD * 1024 * 2);
  f16*   merged = (f16*)alloc((size_t)MPAD * 2048 * 2);
  float* xf     = (float*)alloc((size_t)MPAD * 1024 * 4);
  f16*   xh     = (f16*)alloc((size_t)MPAD * 1024 * 2);
  f16*   vh     = (f16*)alloc((size_t)MPAD * 1024 * 2);
  f16*   ff1    = (f16*)alloc((size_t)MPAD * 2048 * 2);
  float* t1     = (float*)alloc((size_t)MPAD * 1024 * 4);

  conv_f32_f16<<<16000, 256, 0, stream>>>(embed, embed_h, (long)32000 * 1024);
  for (int k = 0; k < 3; ++k) {
    conv_f32_f16<<<1024, 256, 0, stream>>>(P(k, 0), Wm_h[k], (long)1024 * 2048);
    conv_f32_f16<<<512,  256, 0, stream>>>(P(k, 2), Wv_h[k], (long)1024 * 1024);
    conv_f32_f16<<<512,  256, 0, stream>>>(P(k, 4), Wo_h[k], (long)1024 * 1024);
    conv_f32_f16<<<1024, 256, 0, stream>>>(P(k, 6), W1_h[k], (long)2048 * 1024);
    conv_f32_f16<<<1024, 256, 0, stream>>>(P(k, 8), W2_h[k], (long)1024 * 2048);
  }
  gather_h0<<<MROWS, 256, 0, stream>>>(embed, tok, hprev);

  for (int k = 0; k < 3; ++k) {
    merge_rms<<<MROWS, 256, 0, stream>>>(hprev, embed, tok, merged, k + 1);
    gemm_bt<1, 0, 1, 1, 0><<<dim3(8, 16), 256, 0, stream>>>(
        merged, Wm_h[k], P(k, 1), xf, xh, 2048, 1024, 1024L, 0L, MROWS);
    gemm_bt<1, 0, 0, 1, 0><<<dim3(8, 16), 256, 0, stream>>>(
        xh, Wv_h[k], P(k, 3), nullptr, vh, 1024, 1024, 1024L, 0L, MROWS);
    gemm_bt<1, 0, 1, 0, 0><<<dim3(8, 16), 256, 0, stream>>>(
        vh, Wo_h[k], P(k, 5), t1, nullptr, 1024, 1024, 1024L, 0L, MROWS);
    add_ln<<<MROWS, 256, 0, stream>>>(xf, t1, P(k, 10), P(k, 11), xf, xh);
    gemm_bt<1, 1, 0, 1, 0><<<dim3(16, 16), 256, 0, stream>>>(
        xh, W1_h[k], P(k, 7), nullptr, ff1, 1024, 2048, 2048L, 0L, MROWS);
    gemm_bt<1, 0, 1, 0, 0><<<dim3(8, 16), 256, 0, stream>>>(
        ff1, W2_h[k], P(k, 9), t1, nullptr, 2048, 1024, 1024L, 0L, MROWS);
    add_ln<<<MROWS, 256, 0, stream>>>(xf, t1, P(k, 12), P(k, 13), hprev, h_h);
    // logits = h @ embed^T into out[:, :, k, :], 256x256 8-phase kernel
    gemm256<<<dim3(125, 8), 512, 0, stream>>>(
        h_h, embed_h, out, 1024, 96000L, (long)k * 32000, MROWS);
  }
}

// Round 3
// 1135.593 us; speedup vs baseline: 1.2392x; 1.1968x over previous
//
#include <hip/hip_runtime.h>

// SimpleMTP: 3 sequential MTP heads on MI355X.
// f16 MFMA everywhere heavy; f32 residual/norms.
// Logits GEMM: 256x256 8-phase counted-vmcnt schedule + XCD swizzle.
// Small GEMMs: 64x64 2-phase double-buffered (load hidden under compute).
// Wv/Wo fused into Wvo = Wo@Wv (precomputed per call).

#define NPOS   509
#define MROWS  2036
#define MPAD   2048
#define DMODEL 1024

typedef _Float16 f16;
typedef _Float16 f16x8 __attribute__((ext_vector_type(8)));
typedef _Float16 f16x4 __attribute__((ext_vector_type(4)));
typedef float    f32x4 __attribute__((ext_vector_type(4)));

#define MFMA16(a, b, c) __builtin_amdgcn_mfma_f32_16x16x32_f16(a, b, c, 0, 0, 0)
#define VM0 asm volatile("s_waitcnt vmcnt(0)" ::: "memory")
#define BAR asm volatile("s_barrier" ::: "memory")

__device__ __forceinline__ void gld_lds16(const void* g, void* l) {
  __builtin_amdgcn_global_load_lds(
      (const __attribute__((address_space(1))) void*)g,
      (__attribute__((address_space(3))) void*)l, 16, 0, 0);
}

// ---------------- f32 -> f16 convert: embed ----------------
__global__ __launch_bounds__(256) void conv_f32_f16(const float* __restrict__ src,
                                                    f16* __restrict__ dst, long n) {
  long i = ((long)blockIdx.x * 256 + threadIdx.x) * 8;
  if (i + 8 <= n) {
    float4 a = *(const float4*)(src + i);
    float4 b = *(const float4*)(src + i + 4);
    f16x8 o = {(f16)a.x, (f16)a.y, (f16)a.z, (f16)a.w,
               (f16)b.x, (f16)b.y, (f16)b.z, (f16)b.w};
    *(f16x8*)(dst + i) = o;
  }
}

// ---------------- batched weight conversion (12 tensors) ----------------
struct ConvArgs { const float* s[12]; f16* d[12]; long n[12]; };
__global__ __launch_bounds__(256) void conv_many(ConvArgs a) {
  int t = blockIdx.y;
  long i = ((long)blockIdx.x * 256 + threadIdx.x) * 8;
  if (i + 8 <= a.n[t]) {
    const float* src = a.s[t];
    float4 x = *(const float4*)(src + i);
    float4 y = *(const float4*)(src + i + 4);
    f16x8 o = {(f16)x.x, (f16)x.y, (f16)x.z, (f16)x.w,
               (f16)y.x, (f16)y.y, (f16)y.z, (f16)y.w};
    *(f16x8*)(a.d[t] + i) = o;
  }
}

// ---------------- batched 1024x1024 transpose f32->f16 (Wv -> WvT) ----------------
struct TpArgs { const float* s[3]; f16* d[3]; };
__global__ __launch_bounds__(256) void transpose3(TpArgs a) {
  __shared__ float t[32][33];
  int h = blockIdx.z;
  int bx = blockIdx.x * 32, by = blockIdx.y * 32;
  int tx = threadIdx.x & 31, ty = threadIdx.x >> 5;  // ty 0..7
  const float* src = a.s[h];
  f16* dst = a.d[h];
  #pragma unroll
  for (int r = 0; r < 32; r += 8)
    t[ty + r][tx] = src[(long)(by + ty + r) * 1024 + bx + tx];
  __syncthreads();
  #pragma unroll
  for (int r = 0; r < 32; r += 8)
    dst[(long)(bx + ty + r) * 1024 + by + tx] = (f16)t[tx][ty + r];
}

// ---------------- bvo = Wo @ bv + bo (batched over heads) ----------------
struct BvoArgs { const float* Wo[3]; const float* bv[3]; const float* bo[3]; float* out[3]; };
__global__ __launch_bounds__(64) void make_bvo3(BvoArgs a) {
  int h = blockIdx.y, r = blockIdx.x, l = threadIdx.x;
  const float* Wo = a.Wo[h];
  const float* bv = a.bv[h];
  float s = 0.0f;
  for (int k = l; k < 1024; k += 64) s += Wo[(long)r * 1024 + k] * bv[k];
  #pragma unroll
  for (int off = 32; off > 0; off >>= 1) s += __shfl_xor(s, off);
  if (l == 0) a.out[h][r] = s + a.bo[h][r];
}

// ---------------- gather h_prev(0) ----------------
__global__ __launch_bounds__(256) void gather_h0(const float* __restrict__ embed,
                                                 const int* __restrict__ tok,
                                                 float* __restrict__ hprev) {
  int r = blockIdx.x;
  int b = r / NPOS, t = r - b * NPOS;
  const float4* src = (const float4*)(embed + (long)tok[b * 512 + t] * DMODEL);
  float4* dst = (float4*)(hprev + (long)r * DMODEL);
  dst[threadIdx.x] = src[threadIdx.x];
}

__device__ __forceinline__ float2 block_reduce2(float a, float b) {
  #pragma unroll
  for (int off = 32; off > 0; off >>= 1) {
    a += __shfl_xor(a, off);
    b += __shfl_xor(b, off);
  }
  __shared__ float2 red[4];
  int wv = threadIdx.x >> 6;
  if ((threadIdx.x & 63) == 0) red[wv] = make_float2(a, b);
  __syncthreads();
  float2 r0 = red[0], r1 = red[1], r2 = red[2], r3 = red[3];
  return make_float2(r0.x + r1.x + r2.x + r3.x, r0.y + r1.y + r2.y + r3.y);
}

// ---------------- merged = [rmsnorm(h_prev), rmsnorm(tok)] ----------------
__global__ __launch_bounds__(256) void merge_rms(const float* __restrict__ hprev,
                                                 const float* __restrict__ embed,
                                                 const int* __restrict__ tok,
                                                 f16* __restrict__ merged, int koff) {
  int r = blockIdx.x;
  int b = r / NPOS, t = r - b * NPOS;
  int tid = threadIdx.x;
  float4 hv = ((const float4*)(hprev + (long)r * DMODEL))[tid];
  float4 tv = ((const float4*)(embed + (long)tok[b * 512 + t + koff] * DMODEL))[tid];
  float sh = hv.x * hv.x + hv.y * hv.y + hv.z * hv.z + hv.w * hv.w;
  float st = tv.x * tv.x + tv.y * tv.y + tv.z * tv.z + tv.w * tv.w;
  float2 tot = block_reduce2(sh, st);
  float ih = 1.0f / sqrtf(tot.x * (1.0f / DMODEL) + 1e-8f);
  float it = 1.0f / sqrtf(tot.y * (1.0f / DMODEL) + 1e-8f);
  f16x4 oh = {(f16)(hv.x * ih), (f16)(hv.y * ih), (f16)(hv.z * ih), (f16)(hv.w * ih)};
  f16x4 ot = {(f16)(tv.x * it), (f16)(tv.y * it), (f16)(tv.z * it), (f16)(tv.w * it)};
  *(f16x4*)(merged + (long)r * 2048 + tid * 4) = oh;
  *(f16x4*)(merged + (long)r * 2048 + 1024 + tid * 4) = ot;
}

// ---------------- y = LN(x + res) * g + b ----------------
__global__ __launch_bounds__(256) void add_ln(const float* __restrict__ x,
                                              const float* __restrict__ res,
                                              const float* __restrict__ g,
                                              const float* __restrict__ bb,
                                              float* __restrict__ yf,
                                              f16* __restrict__ yh) {
  int r = blockIdx.x, tid = threadIdx.x;
  float4 a = ((const float4*)(x + (long)r * DMODEL))[tid];
  float4 c = ((const float4*)(res + (long)r * DMODEL))[tid];
  a.x += c.x; a.y += c.y; a.z += c.z; a.w += c.w;
  float s  = a.x + a.y + a.z + a.w;
  float ss = a.x * a.x + a.y * a.y + a.z * a.z + a.w * a.w;
  float2 tot = block_reduce2(s, ss);
  float mean = tot.x * (1.0f / DMODEL);
  float var  = tot.y * (1.0f / DMODEL) - mean * mean;
  float inv  = 1.0f / sqrtf(var + 1e-5f);
  float4 gv = ((const float4*)g)[tid];
  float4 bv = ((const float4*)bb)[tid];
  float y0 = (a.x - mean) * inv * gv.x + bv.x;
  float y1 = (a.y - mean) * inv * gv.y + bv.y;
  float y2 = (a.z - mean) * inv * gv.z + bv.z;
  float y3 = (a.w - mean) * inv * gv.w + bv.w;
  float4 o = {y0, y1, y2, y3};
  ((float4*)(yf + (long)r * DMODEL))[tid] = o;
  f16x4 oh = {(f16)y0, (f16)y1, (f16)y2, (f16)y3};
  *(f16x4*)(yh + (long)r * DMODEL + tid * 4) = oh;
}

// ---------------- small GEMM: 64x64 tile, 2-phase double-buffered ----------------
// 4 waves (2x2), wave tile 32x32. Stage of tile t+1 issued BEFORE compute of t;
// one vmcnt(0)+barrier per tile -> global latency hides under MFMA+ds_read.
template <int HAS_BIAS, int RELU, int WF32, int WF16, int MASK>
__global__ __launch_bounds__(256) void gemm_sm(const f16* __restrict__ A,
                                               const f16* __restrict__ B,
                                               const float* __restrict__ bias,
                                               float* __restrict__ Cf,
                                               f16* __restrict__ Ch,
                                               int K, int N, long ldc, long coff,
                                               int mval) {
  __shared__ __align__(16) f16 sA[2][64 * 32];
  __shared__ __align__(16) f16 sB[2][64 * 32];
  const int tid  = threadIdx.x;
  const int lane = tid & 63, wv = tid >> 6;
  const int wm = wv >> 1, wn = wv & 1;
  const int bm = blockIdx.y, bn = blockIdx.x;
  const int lr = lane & 15, lk = lane >> 4;

  const f16* gA = A + ((long)(bm * 64 + (tid >> 2))) * K + (tid & 3) * 8;
  const f16* gB = B + ((long)(bn * 64 + (tid >> 2))) * K + (tid & 3) * 8;

  const int aoff = (wm * 32 + lr) * 32 + lk * 8;  // + mi*512
  const int boff = (wn * 32 + lr) * 32 + lk * 8;  // + ni*512

  f32x4 acc[2][2] = {};

#define SSTAGE(buf, kt)                                \
  gld_lds16(gA + (long)(kt) * 32, &sA[buf][tid * 8]);  \
  gld_lds16(gB + (long)(kt) * 32, &sB[buf][tid * 8]);

  SSTAGE(0, 0);
  VM0; BAR;

  const int nk = K >> 5;
  for (int kt = 0; kt < nk; ++kt) {
    const int cur = kt & 1;
    if (kt + 1 < nk) { SSTAGE(cur ^ 1, kt + 1); }
    f16x8 af0 = *(const f16x8*)&sA[cur][aoff];
    f16x8 af1 = *(const f16x8*)&sA[cur][aoff + 512];
    f16x8 bf0 = *(const f16x8*)&sB[cur][boff];
    f16x8 bf1 = *(const f16x8*)&sB[cur][boff + 512];
    acc[0][0] = MFMA16(af0, bf0, acc[0][0]);
    acc[0][1] = MFMA16(af0, bf1, acc[0][1]);
    acc[1][0] = MFMA16(af1, bf0, acc[1][0]);
    acc[1][1] = MFMA16(af1, bf1, acc[1][1]);
    VM0; BAR;
  }
#undef SSTAGE

  const int row0 = bm * 64 + wm * 32 + lk * 4;
  const int col0 = bn * 64 + wn * 32 + lr;
  #pragma unroll
  for (int mi = 0; mi < 2; ++mi) {
    #pragma unroll
    for (int ni = 0; ni < 2; ++ni) {
      int col = col0 + ni * 16;
      float bs = HAS_BIAS ? bias[col] : 0.0f;
      #pragma unroll
      for (int rg = 0; rg < 4; ++rg) {
        int row = row0 + mi * 16 + rg;
        if (!MASK || row < mval) {
          float v = acc[mi][ni][rg] + bs;
          if (RELU) v = v > 0.0f ? v : 0.0f;
          if (WF32) Cf[(long)row * ldc + coff + col] = v;
          if (WF16) Ch[(long)row * N + col] = (f16)v;
        }
      }
    }
  }
}

// ---------------- logits GEMM: 256x256, BK=64, 8-phase counted vmcnt ----------------
__global__ __launch_bounds__(512, 2) void gemm256(const f16* __restrict__ A,
                                                  const f16* __restrict__ B,
                                                  float* __restrict__ C,
                                                  int K, long ldc, long coff,
                                                  int mval) {
  __shared__ __align__(16) f16 sA[2][2][8192];
  __shared__ __align__(16) f16 sB[2][2][8192];
  const int tid = threadIdx.x;
  const int lane = tid & 63;
  const int wv = tid >> 6;
  const int wm = wv >> 2, wn = wv & 3;
  const int lr = lane & 15, lk = lane >> 4;

  // XCD-aware swizzle: 1000 blocks, nwg%8==0 -> bijective. Each XCD owns one
  // bm row (A panel resident in its L2), bn streams through LLC.
  const int flat = blockIdx.y * 125 + blockIdx.x;
  const int bm = flat & 7, bn = flat >> 3;

  const int srow = tid >> 2;
  const int scol = (tid & 3) * 8;
  const f16* gA = A + (long)(bm * 256 + srow) * K + scol;
  const f16* gB = B + (long)(bn * 256 + srow) * K + scol;
  const long rstep = 128L * (long)K;

  const int aoff = (wm * 128 + lr) * 32 + lk * 8;
  const int boff = (wn * 64  + lr) * 32 + lk * 8;

  f32x4 acc[8][4] = {};

#define STAGE_A(buf, h, ko)                                        \
  gld_lds16(gA + (ko) + (h) * 32, &sA[buf][h][tid * 8]);           \
  gld_lds16(gA + (ko) + (h) * 32 + rstep, &sA[buf][h][tid * 8 + 4096]);
#define STAGE_B(buf, h, ko)                                        \
  gld_lds16(gB + (ko) + (h) * 32, &sB[buf][h][tid * 8]);           \
  gld_lds16(gB + (ko) + (h) * 32 + rstep, &sB[buf][h][tid * 8 + 4096]);
#define VMCNT6  asm volatile("s_waitcnt vmcnt(6)" ::: "memory")

  STAGE_A(0, 0, 0); STAGE_B(0, 0, 0); STAGE_A(0, 1, 0); STAGE_B(0, 1, 0);

  const int nt = K >> 6;
  for (int t = 0; t < nt; ++t) {
    const int cur = t & 1, nxt = cur ^ 1;
    const long kn = (long)((t + 1 < nt) ? (t + 1) : 0) * 64;
    f16x8 af[8], bf[4];

    // phase 1: ksub0, n-frags 0-1
    STAGE_A(nxt, 0, kn);
    VMCNT6;
    BAR;
    #pragma unroll
    for (int mi = 0; mi < 8; ++mi) af[mi] = *(const f16x8*)&sA[cur][0][aoff + mi * 512];
    bf[0] = *(const f16x8*)&sB[cur][0][boff];
    bf[1] = *(const f16x8*)&sB[cur][0][boff + 512];
    __builtin_amdgcn_s_setprio(1);
    #pragma unroll
    for (int mi = 0; mi < 8; ++mi) {
      acc[mi][0] = MFMA16(af[mi], bf[0], acc[mi][0]);
      acc[mi][1] = MFMA16(af[mi], bf[1], acc[mi][1]);
    }
    __builtin_amdgcn_s_setprio(0);
    BAR;

    // phase 2: ksub0, n-frags 2-3
    STAGE_B(nxt, 0, kn);
    BAR;
    bf[2] = *(const f16x8*)&sB[cur][0][boff + 1024];
    bf[3] = *(const f16x8*)&sB[cur][0][boff + 1536];
    __builtin_amdgcn_s_setprio(1);
    #pragma unroll
    for (int mi = 0; mi < 8; ++mi) {
      acc[mi][2] = MFMA16(af[mi], bf[2], acc[mi][2]);
      acc[mi][3] = MFMA16(af[mi], bf[3], acc[mi][3]);
    }
    __builtin_amdgcn_s_setprio(0);
    BAR;

    // phase 3: ksub1, n-frags 0-1
    STAGE_A(nxt, 1, kn);
    VMCNT6;
    BAR;
    #pragma unroll
    for (int mi = 0; mi < 8; ++mi) af[mi] = *(const f16x8*)&sA[cur][1][aoff + mi * 512];
    bf[0] = *(const f16x8*)&sB[cur][1][boff];
    bf[1] = *(const f16x8*)&sB[cur][1][boff + 512];
    __builtin_amdgcn_s_setprio(1);
    #pragma unroll
    for (int mi = 0; mi < 8; ++mi) {
      acc[mi][0] = MFMA16(af[mi], bf[0], acc[mi][0]);
      acc[mi][1] = MFMA16(af[mi], bf[1], acc[mi][1]);
    }
    __builtin_amdgcn_s_setprio(0);
    BAR;

    // phase 4: ksub1, n-frags 2-3
    STAGE_B(nxt, 1, kn);
    BAR;
    bf[2] = *(const f16x8*)&sB[cur][1][boff + 1024];
    bf[3] = *(const f16x8*)&sB[cur][1][boff + 1536];
    __builtin_amdgcn_s_setprio(1);
    #pragma unroll
    for (int mi = 0; mi < 8; ++mi) {
      acc[mi][2] = MFMA16(af[mi], bf[2], acc[mi][2]);
      acc[mi][3] = MFMA16(af[mi], bf[3], acc[mi][3]);
    }
    __builtin_amdgcn_s_setprio(0);
    BAR;
  }
  VM0;

  const int row0 = bm * 256 + wm * 128 + lk * 4;
  const int col0 = bn * 256 + wn * 64 + lr;
  #pragma unroll
  for (int mi = 0; mi < 8; ++mi) {
    #pragma unroll
    for (int ni = 0; ni < 4; ++ni) {
      int col = col0 + ni * 16;
      #pragma unroll
      for (int rg = 0; rg < 4; ++rg) {
        int row = row0 + mi * 16 + rg;
        if (row < mval) C[(long)row * ldc + coff + col] = acc[mi][ni][rg];
      }
    }
  }
#undef STAGE_A
#undef STAGE_B
#undef VMCNT6
}

// ---------------- host-side orchestration ----------------
extern "C" void kernel_launch(void* const* d_in, const int* in_sizes, int n_in,
                              void* d_out, int out_size, void* d_ws, size_t ws_size,
                              hipStream_t stream) {
  const int*   tok   = (const int*)d_in[0];
  const float* embed = (const float*)d_in[1];
  auto P = [&](int k, int j) { return (const float*)d_in[2 + k * 14 + j]; };
  float* out = (float*)d_out;

  char* w = (char*)d_ws;
  auto alloc = [&](size_t bytes) { char* p = w; w += bytes; return p; };

  f16* embed_h = (f16*)alloc((size_t)32000 * 1024 * 2);
  f16 *Wm_h[3], *Wo_h[3], *W1_h[3], *W2_h[3], *Wvo_h[3];
  for (int k = 0; k < 3; ++k) {
    Wm_h[k]  = (f16*)alloc((size_t)1024 * 2048 * 2);
    Wo_h[k]  = (f16*)alloc((size_t)1024 * 1024 * 2);
    W1_h[k]  = (f16*)alloc((size_t)2048 * 1024 * 2);
    W2_h[k]  = (f16*)alloc((size_t)1024 * 2048 * 2);
    Wvo_h[k] = (f16*)alloc((size_t)1024 * 1024 * 2);
  }
  float* hprev  = (float*)alloc((size_t)MPAD * 1024 * 4);
  f16*   h_h    = (f16*)alloc((size_t)MPAD * 1024 * 2);
  f16*   merged = (f16*)alloc((size_t)MPAD * 2048 * 2);
  float* xf     = (float*)alloc((size_t)MPAD * 1024 * 4);
  f16*   xh     = (f16*)alloc((size_t)MPAD * 1024 * 2);
  f16*   ff1    = (f16*)alloc((size_t)MPAD * 2048 * 2);
  float* t1     = (float*)alloc((size_t)MPAD * 1024 * 4);
  float* bvo    = (float*)alloc(3 * 1024 * 4);
  // WvT scratch overlays `merged` (merged written only later, stream-ordered)
  f16* WvT[3] = {merged, merged + (size_t)1024 * 1024, merged + (size_t)2 * 1024 * 1024};

  // ---- prep: conversions, Wvo = Wo @ Wv, bvo = Wo @ bv + bo ----
  conv_f32_f16<<<16000, 256, 0, stream>>>(embed, embed_h, (long)32000 * 1024);

  ConvArgs ca;
  for (int k = 0; k < 3; ++k) {
    ca.s[k*4+0] = P(k, 0); ca.d[k*4+0] = Wm_h[k]; ca.n[k*4+0] = (long)1024 * 2048;
    ca.s[k*4+1] = P(k, 4); ca.d[k*4+1] = Wo_h[k]; ca.n[k*4+1] = (long)1024 * 1024;
    ca.s[k*4+2] = P(k, 6); ca.d[k*4+2] = W1_h[k]; ca.n[k*4+2] = (long)2048 * 1024;
    ca.s[k*4+3] = P(k, 8); ca.d[k*4+3] = W2_h[k]; ca.n[k*4+3] = (long)1024 * 2048;
  }
  conv_many<<<dim3(1024, 12), 256, 0, stream>>>(ca);

  TpArgs ta;
  for (int k = 0; k < 3; ++k) { ta.s[k] = P(k, 2); ta.d[k] = WvT[k]; }
  transpose3<<<dim3(32, 32, 3), 256, 0, stream>>>(ta);

  for (int k = 0; k < 3; ++k)
    gemm_sm<0, 0, 0, 1, 0><<<dim3(16, 16), 256, 0, stream>>>(
        Wo_h[k], WvT[k], nullptr, nullptr, Wvo_h[k], 1024, 1024, 1024L, 0L, 1024);

  BvoArgs ba;
  for (int k = 0; k < 3; ++k) {
    ba.Wo[k] = P(k, 4); ba.bv[k] = P(k, 3); ba.bo[k] = P(k, 5); ba.out[k] = bvo + k * 1024;
  }
  make_bvo3<<<dim3(1024, 3), 64, 0, stream>>>(ba);

  gather_h0<<<MROWS, 256, 0, stream>>>(embed, tok, hprev);

  // ---- 3 heads ----
  for (int k = 0; k < 3; ++k) {
    merge_rms<<<MROWS, 256, 0, stream>>>(hprev, embed, tok, merged, k + 1);
    // x = merged @ Wmerge^T + bmerge
    gemm_sm<1, 0, 1, 1, 0><<<dim3(16, 32), 256, 0, stream>>>(
        merged, Wm_h[k], P(k, 1), xf, xh, 2048, 1024, 1024L, 0L, MROWS);
    // attn = x @ Wvo^T + bvo
    gemm_sm<1, 0, 1, 0, 0><<<dim3(16, 32), 256, 0, stream>>>(
        xh, Wvo_h[k], bvo + k * 1024, t1, nullptr, 1024, 1024, 1024L, 0L, MROWS);
    add_ln<<<MROWS, 256, 0, stream>>>(xf, t1, P(k, 10), P(k, 11), xf, xh);
    // ff1 = relu(x @ W1^T + b1)
    gemm_sm<1, 1, 0, 1, 0><<<dim3(32, 32), 256, 0, stream>>>(
        xh, W1_h[k], P(k, 7), nullptr, ff1, 1024, 2048, 2048L, 0L, MROWS);
    // ff = ff1 @ W2^T + b2
    gemm_sm<1, 0, 1, 0, 0><<<dim3(16, 32), 256, 0, stream>>>(
        ff1, W2_h[k], P(k, 9), t1, nullptr, 2048, 1024, 1024L, 0L, MROWS);
    add_ln<<<MROWS, 256, 0, stream>>>(xf, t1, P(k, 12), P(k, 13), hprev, h_h);
    // logits = h @ embed^T into out[:, :, k, :]
    gemm256<<<dim3(125, 8), 512, 0, stream>>>(
        h_h, embed_h, out, 1024, 96000L, (long)k * 32000, MROWS);
  }
}

// Round 4
// 1125.431 us; speedup vs baseline: 1.2504x; 1.0090x over previous
//
#include <hip/hip_runtime.h>

// SimpleMTP: 3 sequential MTP heads on MI355X.
// f16 MFMA everywhere heavy; f32 residual/norms.
// Logits GEMM: 256x256 8-phase counted-vmcnt schedule + XCD swizzle.
// Small GEMMs: 64x64, 3-buffer depth-2 prefetch (vmcnt(2), 1 barrier/iter).
// Wv/Wo fused into Wvo = Wo@Wv (precomputed per call, batched launch).

#define NPOS   509
#define MROWS  2036
#define MPAD   2048
#define DMODEL 1024

typedef _Float16 f16;
typedef _Float16 f16x8 __attribute__((ext_vector_type(8)));
typedef _Float16 f16x4 __attribute__((ext_vector_type(4)));
typedef float    f32x4 __attribute__((ext_vector_type(4)));

#define MFMA16(a, b, c) __builtin_amdgcn_mfma_f32_16x16x32_f16(a, b, c, 0, 0, 0)
#define VM0 asm volatile("s_waitcnt vmcnt(0)" ::: "memory")
#define VM2 asm volatile("s_waitcnt vmcnt(2)" ::: "memory")
#define BAR asm volatile("s_barrier" ::: "memory")

__device__ __forceinline__ void gld_lds16(const void* g, void* l) {
  __builtin_amdgcn_global_load_lds(
      (const __attribute__((address_space(1))) void*)g,
      (__attribute__((address_space(3))) void*)l, 16, 0, 0);
}

// ---------------- f32 -> f16 convert: embed ----------------
__global__ __launch_bounds__(256) void conv_f32_f16(const float* __restrict__ src,
                                                    f16* __restrict__ dst, long n) {
  long i = ((long)blockIdx.x * 256 + threadIdx.x) * 8;
  if (i + 8 <= n) {
    float4 a = *(const float4*)(src + i);
    float4 b = *(const float4*)(src + i + 4);
    f16x8 o = {(f16)a.x, (f16)a.y, (f16)a.z, (f16)a.w,
               (f16)b.x, (f16)b.y, (f16)b.z, (f16)b.w};
    *(f16x8*)(dst + i) = o;
  }
}

// ---------------- batched weight conversion (12 tensors) ----------------
struct ConvArgs { const float* s[12]; f16* d[12]; long n[12]; };
__global__ __launch_bounds__(256) void conv_many(ConvArgs a) {
  int t = blockIdx.y;
  long i = ((long)blockIdx.x * 256 + threadIdx.x) * 8;
  if (i + 8 <= a.n[t]) {
    const float* src = a.s[t];
    float4 x = *(const float4*)(src + i);
    float4 y = *(const float4*)(src + i + 4);
    f16x8 o = {(f16)x.x, (f16)x.y, (f16)x.z, (f16)x.w,
               (f16)y.x, (f16)y.y, (f16)y.z, (f16)y.w};
    *(f16x8*)(a.d[t] + i) = o;
  }
}

// ---------------- batched 1024x1024 transpose f32->f16 (Wv -> WvT) ----------------
struct TpArgs { const float* s[3]; f16* d[3]; };
__global__ __launch_bounds__(256) void transpose3(TpArgs a) {
  __shared__ float t[32][33];
  int h = blockIdx.z;
  int bx = blockIdx.x * 32, by = blockIdx.y * 32;
  int tx = threadIdx.x & 31, ty = threadIdx.x >> 5;  // ty 0..7
  const float* src = a.s[h];
  f16* dst = a.d[h];
  #pragma unroll
  for (int r = 0; r < 32; r += 8)
    t[ty + r][tx] = src[(long)(by + ty + r) * 1024 + bx + tx];
  __syncthreads();
  #pragma unroll
  for (int r = 0; r < 32; r += 8)
    dst[(long)(bx + ty + r) * 1024 + by + tx] = (f16)t[tx][ty + r];
}

// ---------------- bvo = Wo @ bv + bo (batched over heads) ----------------
struct BvoArgs { const float* Wo[3]; const float* bv[3]; const float* bo[3]; float* out[3]; };
__global__ __launch_bounds__(64) void make_bvo3(BvoArgs a) {
  int h = blockIdx.y, r = blockIdx.x, l = threadIdx.x;
  const float* Wo = a.Wo[h];
  const float* bv = a.bv[h];
  float s = 0.0f;
  for (int k = l; k < 1024; k += 64) s += Wo[(long)r * 1024 + k] * bv[k];
  #pragma unroll
  for (int off = 32; off > 0; off >>= 1) s += __shfl_xor(s, off);
  if (l == 0) a.out[h][r] = s + a.bo[h][r];
}

__device__ __forceinline__ float2 block_reduce2(float a, float b) {
  #pragma unroll
  for (int off = 32; off > 0; off >>= 1) {
    a += __shfl_xor(a, off);
    b += __shfl_xor(b, off);
  }
  __shared__ float2 red[4];
  int wv = threadIdx.x >> 6;
  if ((threadIdx.x & 63) == 0) red[wv] = make_float2(a, b);
  __syncthreads();
  float2 r0 = red[0], r1 = red[1], r2 = red[2], r3 = red[3];
  return make_float2(r0.x + r1.x + r2.x + r3.x, r0.y + r1.y + r2.y + r3.y);
}

// ---------------- merged = [rmsnorm(h_prev), rmsnorm(tok)] ----------------
// hsel >= 0: h_prev row comes from embed[tok[b, t+hsel]] (head 0; no gather pass).
__global__ __launch_bounds__(256) void merge_rms(const float* __restrict__ hprev,
                                                 const float* __restrict__ embed,
                                                 const int* __restrict__ tok,
                                                 f16* __restrict__ merged, int koff,
                                                 int hsel) {
  int r = blockIdx.x;
  int b = r / NPOS, t = r - b * NPOS;
  int tid = threadIdx.x;
  const float* hrow = (hsel >= 0)
      ? embed + (long)tok[b * 512 + t + hsel] * DMODEL
      : hprev + (long)r * DMODEL;
  float4 hv = ((const float4*)hrow)[tid];
  float4 tv = ((const float4*)(embed + (long)tok[b * 512 + t + koff] * DMODEL))[tid];
  float sh = hv.x * hv.x + hv.y * hv.y + hv.z * hv.z + hv.w * hv.w;
  float st = tv.x * tv.x + tv.y * tv.y + tv.z * tv.z + tv.w * tv.w;
  float2 tot = block_reduce2(sh, st);
  float ih = 1.0f / sqrtf(tot.x * (1.0f / DMODEL) + 1e-8f);
  float it = 1.0f / sqrtf(tot.y * (1.0f / DMODEL) + 1e-8f);
  f16x4 oh = {(f16)(hv.x * ih), (f16)(hv.y * ih), (f16)(hv.z * ih), (f16)(hv.w * ih)};
  f16x4 ot = {(f16)(tv.x * it), (f16)(tv.y * it), (f16)(tv.z * it), (f16)(tv.w * it)};
  *(f16x4*)(merged + (long)r * 2048 + tid * 4) = oh;
  *(f16x4*)(merged + (long)r * 2048 + 1024 + tid * 4) = ot;
}

// ---------------- y = LN(x + res) * g + b ----------------
__global__ __launch_bounds__(256) void add_ln(const float* __restrict__ x,
                                              const float* __restrict__ res,
                                              const float* __restrict__ g,
                                              const float* __restrict__ bb,
                                              float* __restrict__ yf,
                                              f16* __restrict__ yh) {
  int r = blockIdx.x, tid = threadIdx.x;
  float4 a = ((const float4*)(x + (long)r * DMODEL))[tid];
  float4 c = ((const float4*)(res + (long)r * DMODEL))[tid];
  a.x += c.x; a.y += c.y; a.z += c.z; a.w += c.w;
  float s  = a.x + a.y + a.z + a.w;
  float ss = a.x * a.x + a.y * a.y + a.z * a.z + a.w * a.w;
  float2 tot = block_reduce2(s, ss);
  float mean = tot.x * (1.0f / DMODEL);
  float var  = tot.y * (1.0f / DMODEL) - mean * mean;
  float inv  = 1.0f / sqrtf(var + 1e-5f);
  float4 gv = ((const float4*)g)[tid];
  float4 bv = ((const float4*)bb)[tid];
  float y0 = (a.x - mean) * inv * gv.x + bv.x;
  float y1 = (a.y - mean) * inv * gv.y + bv.y;
  float y2 = (a.z - mean) * inv * gv.z + bv.z;
  float y3 = (a.w - mean) * inv * gv.w + bv.w;
  float4 o = {y0, y1, y2, y3};
  ((float4*)(yf + (long)r * DMODEL))[tid] = o;
  f16x4 oh = {(f16)y0, (f16)y1, (f16)y2, (f16)y3};
  *(f16x4*)(yh + (long)r * DMODEL + tid * 4) = oh;
}

// ---------------- small GEMM: 64x64 tile, 3-buffer depth-2 prefetch ----------------
// 4 waves (2x2), wave tile 32x32. Loads for tile t+2 issued at iter t (right
// after the barrier); vmcnt(2) waits only for tile t's 2 loads, leaving t+1's
// in flight -> ~2 iterations of latency slack. One barrier per iteration.
// Buffer safety: BAR(t) proves all waves finished reading buf[(t+2)%3] at t-1.
template <int HAS_BIAS, int RELU, int WF32, int WF16, int MASK>
__global__ __launch_bounds__(256) void gemm_sm(const f16* __restrict__ A,
                                               const f16* __restrict__ B,
                                               const float* __restrict__ bias,
                                               float* __restrict__ Cf,
                                               f16* __restrict__ Ch,
                                               int K, int N, long ldc, long coff,
                                               int mval, long zsA, long zsB, long zsC) {
  __shared__ __align__(16) f16 sA[3][2048];
  __shared__ __align__(16) f16 sB[3][2048];
  const int tid  = threadIdx.x;
  const int lane = tid & 63, wv = tid >> 6;
  const int wm = wv >> 1, wn = wv & 1;
  const int bm = blockIdx.y, bn = blockIdx.x;
  const int lr = lane & 15, lk = lane >> 4;

  A += (long)blockIdx.z * zsA;
  B += (long)blockIdx.z * zsB;
  Ch += (long)blockIdx.z * zsC;

  const f16* gA = A + ((long)(bm * 64 + (tid >> 2))) * K + (tid & 3) * 8;
  const f16* gB = B + ((long)(bn * 64 + (tid >> 2))) * K + (tid & 3) * 8;

  const int aoff = (wm * 32 + lr) * 32 + lk * 8;  // + mi*512
  const int boff = (wn * 32 + lr) * 32 + lk * 8;  // + ni*512

  f32x4 acc[2][2] = {};

#define SSTAGE(buf, kt)                                \
  gld_lds16(gA + (long)(kt) * 32, &sA[buf][tid * 8]);  \
  gld_lds16(gB + (long)(kt) * 32, &sB[buf][tid * 8]);

  const int nk = K >> 5;  // >= 32 for all uses
  SSTAGE(0, 0);
  SSTAGE(1, 1);

  int cur = 0, stg = 2;
  for (int kt = 0; kt < nk; ++kt) {
    if (kt + 1 < nk) { VM2; } else { VM0; }
    BAR;
    if (kt + 2 < nk) { SSTAGE(stg, kt + 2); }
    f16x8 af0 = *(const f16x8*)&sA[cur][aoff];
    f16x8 af1 = *(const f16x8*)&sA[cur][aoff + 512];
    f16x8 bf0 = *(const f16x8*)&sB[cur][boff];
    f16x8 bf1 = *(const f16x8*)&sB[cur][boff + 512];
    acc[0][0] = MFMA16(af0, bf0, acc[0][0]);
    acc[0][1] = MFMA16(af0, bf1, acc[0][1]);
    acc[1][0] = MFMA16(af1, bf0, acc[1][0]);
    acc[1][1] = MFMA16(af1, bf1, acc[1][1]);
    cur = cur == 2 ? 0 : cur + 1;
    stg = stg == 2 ? 0 : stg + 1;
  }
#undef SSTAGE

  const int row0 = bm * 64 + wm * 32 + lk * 4;
  const int col0 = bn * 64 + wn * 32 + lr;
  #pragma unroll
  for (int mi = 0; mi < 2; ++mi) {
    #pragma unroll
    for (int ni = 0; ni < 2; ++ni) {
      int col = col0 + ni * 16;
      float bs = HAS_BIAS ? bias[col] : 0.0f;
      #pragma unroll
      for (int rg = 0; rg < 4; ++rg) {
        int row = row0 + mi * 16 + rg;
        if (!MASK || row < mval) {
          float v = acc[mi][ni][rg] + bs;
          if (RELU) v = v > 0.0f ? v : 0.0f;
          if (WF32) Cf[(long)row * ldc + coff + col] = v;
          if (WF16) Ch[(long)row * N + col] = (f16)v;
        }
      }
    }
  }
}

// ---------------- logits GEMM: 256x256, BK=64, 8-phase counted vmcnt ----------------
__global__ __launch_bounds__(512, 2) void gemm256(const f16* __restrict__ A,
                                                  const f16* __restrict__ B,
                                                  float* __restrict__ C,
                                                  int K, long ldc, long coff,
                                                  int mval) {
  __shared__ __align__(16) f16 sA[2][2][8192];
  __shared__ __align__(16) f16 sB[2][2][8192];
  const int tid = threadIdx.x;
  const int lane = tid & 63;
  const int wv = tid >> 6;
  const int wm = wv >> 2, wn = wv & 3;
  const int lr = lane & 15, lk = lane >> 4;

  // XCD-aware swizzle: 1000 blocks, nwg%8==0 -> bijective.
  const int flat = blockIdx.y * 125 + blockIdx.x;
  const int bm = flat & 7, bn = flat >> 3;

  const int srow = tid >> 2;
  const int scol = (tid & 3) * 8;
  const f16* gA = A + (long)(bm * 256 + srow) * K + scol;
  const f16* gB = B + (long)(bn * 256 + srow) * K + scol;
  const long rstep = 128L * (long)K;

  const int aoff = (wm * 128 + lr) * 32 + lk * 8;
  const int boff = (wn * 64  + lr) * 32 + lk * 8;

  f32x4 acc[8][4] = {};

#define STAGE_A(buf, h, ko)                                        \
  gld_lds16(gA + (ko) + (h) * 32, &sA[buf][h][tid * 8]);           \
  gld_lds16(gA + (ko) + (h) * 32 + rstep, &sA[buf][h][tid * 8 + 4096]);
#define STAGE_B(buf, h, ko)                                        \
  gld_lds16(gB + (ko) + (h) * 32, &sB[buf][h][tid * 8]);           \
  gld_lds16(gB + (ko) + (h) * 32 + rstep, &sB[buf][h][tid * 8 + 4096]);
#define VMCNT6  asm volatile("s_waitcnt vmcnt(6)" ::: "memory")

  STAGE_A(0, 0, 0); STAGE_B(0, 0, 0); STAGE_A(0, 1, 0); STAGE_B(0, 1, 0);

  const int nt = K >> 6;
  for (int t = 0; t < nt; ++t) {
    const int cur = t & 1, nxt = cur ^ 1;
    const long kn = (long)((t + 1 < nt) ? (t + 1) : 0) * 64;
    f16x8 af[8], bf[4];

    // phase 1: ksub0, n-frags 0-1
    STAGE_A(nxt, 0, kn);
    VMCNT6;
    BAR;
    #pragma unroll
    for (int mi = 0; mi < 8; ++mi) af[mi] = *(const f16x8*)&sA[cur][0][aoff + mi * 512];
    bf[0] = *(const f16x8*)&sB[cur][0][boff];
    bf[1] = *(const f16x8*)&sB[cur][0][boff + 512];
    __builtin_amdgcn_s_setprio(1);
    #pragma unroll
    for (int mi = 0; mi < 8; ++mi) {
      acc[mi][0] = MFMA16(af[mi], bf[0], acc[mi][0]);
      acc[mi][1] = MFMA16(af[mi], bf[1], acc[mi][1]);
    }
    __builtin_amdgcn_s_setprio(0);
    BAR;

    // phase 2: ksub0, n-frags 2-3
    STAGE_B(nxt, 0, kn);
    BAR;
    bf[2] = *(const f16x8*)&sB[cur][0][boff + 1024];
    bf[3] = *(const f16x8*)&sB[cur][0][boff + 1536];
    __builtin_amdgcn_s_setprio(1);
    #pragma unroll
    for (int mi = 0; mi < 8; ++mi) {
      acc[mi][2] = MFMA16(af[mi], bf[2], acc[mi][2]);
      acc[mi][3] = MFMA16(af[mi], bf[3], acc[mi][3]);
    }
    __builtin_amdgcn_s_setprio(0);
    BAR;

    // phase 3: ksub1, n-frags 0-1
    STAGE_A(nxt, 1, kn);
    VMCNT6;
    BAR;
    #pragma unroll
    for (int mi = 0; mi < 8; ++mi) af[mi] = *(const f16x8*)&sA[cur][1][aoff + mi * 512];
    bf[0] = *(const f16x8*)&sB[cur][1][boff];
    bf[1] = *(const f16x8*)&sB[cur][1][boff + 512];
    __builtin_amdgcn_s_setprio(1);
    #pragma unroll
    for (int mi = 0; mi < 8; ++mi) {
      acc[mi][0] = MFMA16(af[mi], bf[0], acc[mi][0]);
      acc[mi][1] = MFMA16(af[mi], bf[1], acc[mi][1]);
    }
    __builtin_amdgcn_s_setprio(0);
    BAR;

    // phase 4: ksub1, n-frags 2-3
    STAGE_B(nxt, 1, kn);
    BAR;
    bf[2] = *(const f16x8*)&sB[cur][1][boff + 1024];
    bf[3] = *(const f16x8*)&sB[cur][1][boff + 1536];
    __builtin_amdgcn_s_setprio(1);
    #pragma unroll
    for (int mi = 0; mi < 8; ++mi) {
      acc[mi][2] = MFMA16(af[mi], bf[2], acc[mi][2]);
      acc[mi][3] = MFMA16(af[mi], bf[3], acc[mi][3]);
    }
    __builtin_amdgcn_s_setprio(0);
    BAR;
  }
  VM0;

  const int row0 = bm * 256 + wm * 128 + lk * 4;
  const int col0 = bn * 256 + wn * 64 + lr;
  #pragma unroll
  for (int mi = 0; mi < 8; ++mi) {
    #pragma unroll
    for (int ni = 0; ni < 4; ++ni) {
      int col = col0 + ni * 16;
      #pragma unroll
      for (int rg = 0; rg < 4; ++rg) {
        int row = row0 + mi * 16 + rg;
        if (row < mval) C[(long)row * ldc + coff + col] = acc[mi][ni][rg];
      }
    }
  }
#undef STAGE_A
#undef STAGE_B
#undef VMCNT6
}

// ---------------- host-side orchestration ----------------
extern "C" void kernel_launch(void* const* d_in, const int* in_sizes, int n_in,
                              void* d_out, int out_size, void* d_ws, size_t ws_size,
                              hipStream_t stream) {
  const int*   tok   = (const int*)d_in[0];
  const float* embed = (const float*)d_in[1];
  auto P = [&](int k, int j) { return (const float*)d_in[2 + k * 14 + j]; };
  float* out = (float*)d_out;

  char* w = (char*)d_ws;
  auto alloc = [&](size_t bytes) { char* p = w; w += bytes; return p; };
  const size_t MM = (size_t)1024 * 1024;

  f16* embed_h = (f16*)alloc((size_t)32000 * 1024 * 2);
  f16* Wo_all  = (f16*)alloc(3 * MM * 2);   // contiguous per-head Wo
  f16* Wvo_all = (f16*)alloc(3 * MM * 2);   // contiguous per-head Wvo
  f16 *Wm_h[3], *W1_h[3], *W2_h[3];
  for (int k = 0; k < 3; ++k) {
    Wm_h[k]  = (f16*)alloc((size_t)1024 * 2048 * 2);
    W1_h[k]  = (f16*)alloc((size_t)2048 * 1024 * 2);
    W2_h[k]  = (f16*)alloc((size_t)1024 * 2048 * 2);
  }
  float* hprev  = (float*)alloc((size_t)MPAD * 1024 * 4);
  f16*   h_h    = (f16*)alloc((size_t)MPAD * 1024 * 2);
  f16*   merged = (f16*)alloc((size_t)MPAD * 2048 * 2);
  float* xf     = (float*)alloc((size_t)MPAD * 1024 * 4);
  f16*   xh     = (f16*)alloc((size_t)MPAD * 1024 * 2);
  f16*   ff1    = (f16*)alloc((size_t)MPAD * 2048 * 2);
  float* t1     = (float*)alloc((size_t)MPAD * 1024 * 4);
  float* bvo    = (float*)alloc(3 * 1024 * 4);
  // WvT scratch overlays `merged` (merged written only later, stream-ordered)
  f16* WvT_all = merged;  // 3*MM f16 fits in merged (4M f16)

  // ---- prep ----
  conv_f32_f16<<<16000, 256, 0, stream>>>(embed, embed_h, (long)32000 * 1024);

  ConvArgs ca;
  for (int k = 0; k < 3; ++k) {
    ca.s[k*4+0] = P(k, 0); ca.d[k*4+0] = Wm_h[k];        ca.n[k*4+0] = (long)1024 * 2048;
    ca.s[k*4+1] = P(k, 4); ca.d[k*4+1] = Wo_all + k*MM;  ca.n[k*4+1] = (long)1024 * 1024;
    ca.s[k*4+2] = P(k, 6); ca.d[k*4+2] = W1_h[k];        ca.n[k*4+2] = (long)2048 * 1024;
    ca.s[k*4+3] = P(k, 8); ca.d[k*4+3] = W2_h[k];        ca.n[k*4+3] = (long)1024 * 2048;
  }
  conv_many<<<dim3(1024, 12), 256, 0, stream>>>(ca);

  TpArgs ta;
  for (int k = 0; k < 3; ++k) { ta.s[k] = P(k, 2); ta.d[k] = WvT_all + k * MM; }
  transpose3<<<dim3(32, 32, 3), 256, 0, stream>>>(ta);

  // Wvo[k] = Wo[k] @ WvT[k]  (batched over z)
  gemm_sm<0, 0, 0, 1, 0><<<dim3(16, 16, 3), 256, 0, stream>>>(
      Wo_all, WvT_all, nullptr, nullptr, Wvo_all, 1024, 1024, 1024L, 0L, 1024,
      (long)MM, (long)MM, (long)MM);

  BvoArgs ba;
  for (int k = 0; k < 3; ++k) {
    ba.Wo[k] = P(k, 4); ba.bv[k] = P(k, 3); ba.bo[k] = P(k, 5); ba.out[k] = bvo + k * 1024;
  }
  make_bvo3<<<dim3(1024, 3), 64, 0, stream>>>(ba);

  // ---- 3 heads ----
  for (int k = 0; k < 3; ++k) {
    merge_rms<<<MROWS, 256, 0, stream>>>(hprev, embed, tok, merged, k + 1,
                                         k == 0 ? 0 : -1);
    // x = merged @ Wmerge^T + bmerge
    gemm_sm<1, 0, 1, 1, 0><<<dim3(16, 32), 256, 0, stream>>>(
        merged, Wm_h[k], P(k, 1), xf, xh, 2048, 1024, 1024L, 0L, MROWS, 0L, 0L, 0L);
    // attn = x @ Wvo^T + bvo
    gemm_sm<1, 0, 1, 0, 0><<<dim3(16, 32), 256, 0, stream>>>(
        xh, Wvo_all + k * MM, bvo + k * 1024, t1, nullptr, 1024, 1024, 1024L, 0L,
        MROWS, 0L, 0L, 0L);
    add_ln<<<MROWS, 256, 0, stream>>>(xf, t1, P(k, 10), P(k, 11), xf, xh);
    // ff1 = relu(x @ W1^T + b1)
    gemm_sm<1, 1, 0, 1, 0><<<dim3(32, 32), 256, 0, stream>>>(
        xh, W1_h[k], P(k, 7), nullptr, ff1, 1024, 2048, 2048L, 0L, MROWS, 0L, 0L, 0L);
    // ff = ff1 @ W2^T + b2
    gemm_sm<1, 0, 1, 0, 0><<<dim3(16, 32), 256, 0, stream>>>(
        ff1, W2_h[k], P(k, 9), t1, nullptr, 2048, 1024, 1024L, 0L, MROWS, 0L, 0L, 0L);
    add_ln<<<MROWS, 256, 0, stream>>>(xf, t1, P(k, 12), P(k, 13), hprev, h_h);
    // logits = h @ embed^T into out[:, :, k, :]
    gemm256<<<dim3(125, 8), 512, 0, stream>>>(
        h_h, embed_h, out, 1024, 96000L, (long)k * 32000, MROWS);
  }
}

// Round 5
// 1036.740 us; speedup vs baseline: 1.3574x; 1.0855x over previous
//
#include <hip/hip_runtime.h>

// SimpleMTP: 3 sequential MTP heads on MI355X.
// f16 MFMA everywhere heavy; f32 residual/norms.
// Logits: ONE 256x256 GEMM (M=6144=3 heads), BK=32 4-slot ring, vmcnt(10)
//         deep prefetch (covers L3 latency), XCD-aware A-resident swizzle.
// Small GEMMs: 64x64, 3-buffer depth-2 prefetch.
// Wv/Wo fused into Wvo = Wo@Wv (precomputed per call).

#define NPOS   509
#define MROWS  2036
#define MPAD   2048
#define DMODEL 1024

typedef _Float16 f16;
typedef _Float16 f16x8 __attribute__((ext_vector_type(8)));
typedef _Float16 f16x4 __attribute__((ext_vector_type(4)));
typedef float    f32x4 __attribute__((ext_vector_type(4)));

#define MFMA16(a, b, c) __builtin_amdgcn_mfma_f32_16x16x32_f16(a, b, c, 0, 0, 0)
#define VM0  asm volatile("s_waitcnt vmcnt(0)" ::: "memory")
#define VM2  asm volatile("s_waitcnt vmcnt(2)" ::: "memory")
#define VM10 asm volatile("s_waitcnt vmcnt(10)" ::: "memory")
#define BAR  asm volatile("s_barrier" ::: "memory")

__device__ __forceinline__ void gld_lds16(const void* g, void* l) {
  __builtin_amdgcn_global_load_lds(
      (const __attribute__((address_space(1))) void*)g,
      (__attribute__((address_space(3))) void*)l, 16, 0, 0);
}

// ---------------- f32 -> f16 convert: embed ----------------
__global__ __launch_bounds__(256) void conv_f32_f16(const float* __restrict__ src,
                                                    f16* __restrict__ dst, long n) {
  long i = ((long)blockIdx.x * 256 + threadIdx.x) * 8;
  if (i + 8 <= n) {
    float4 a = *(const float4*)(src + i);
    float4 b = *(const float4*)(src + i + 4);
    f16x8 o = {(f16)a.x, (f16)a.y, (f16)a.z, (f16)a.w,
               (f16)b.x, (f16)b.y, (f16)b.z, (f16)b.w};
    *(f16x8*)(dst + i) = o;
  }
}

// ---------------- batched weight conversion (12 tensors) ----------------
struct ConvArgs { const float* s[12]; f16* d[12]; long n[12]; };
__global__ __launch_bounds__(256) void conv_many(ConvArgs a) {
  int t = blockIdx.y;
  long i = ((long)blockIdx.x * 256 + threadIdx.x) * 8;
  if (i + 8 <= a.n[t]) {
    const float* src = a.s[t];
    float4 x = *(const float4*)(src + i);
    float4 y = *(const float4*)(src + i + 4);
    f16x8 o = {(f16)x.x, (f16)x.y, (f16)x.z, (f16)x.w,
               (f16)y.x, (f16)y.y, (f16)y.z, (f16)y.w};
    *(f16x8*)(a.d[t] + i) = o;
  }
}

// ---------------- batched 1024x1024 transpose f32->f16 (Wv -> WvT) ----------------
struct TpArgs { const float* s[3]; f16* d[3]; };
__global__ __launch_bounds__(256) void transpose3(TpArgs a) {
  __shared__ float t[32][33];
  int h = blockIdx.z;
  int bx = blockIdx.x * 32, by = blockIdx.y * 32;
  int tx = threadIdx.x & 31, ty = threadIdx.x >> 5;
  const float* src = a.s[h];
  f16* dst = a.d[h];
  #pragma unroll
  for (int r = 0; r < 32; r += 8)
    t[ty + r][tx] = src[(long)(by + ty + r) * 1024 + bx + tx];
  __syncthreads();
  #pragma unroll
  for (int r = 0; r < 32; r += 8)
    dst[(long)(bx + ty + r) * 1024 + by + tx] = (f16)t[tx][ty + r];
}

// ---------------- bvo = Wo @ bv + bo (batched over heads) ----------------
struct BvoArgs { const float* Wo[3]; const float* bv[3]; const float* bo[3]; float* out[3]; };
__global__ __launch_bounds__(64) void make_bvo3(BvoArgs a) {
  int h = blockIdx.y, r = blockIdx.x, l = threadIdx.x;
  const float* Wo = a.Wo[h];
  const float* bv = a.bv[h];
  float s = 0.0f;
  for (int k = l; k < 1024; k += 64) s += Wo[(long)r * 1024 + k] * bv[k];
  #pragma unroll
  for (int off = 32; off > 0; off >>= 1) s += __shfl_xor(s, off);
  if (l == 0) a.out[h][r] = s + a.bo[h][r];
}

__device__ __forceinline__ float2 block_reduce2(float a, float b) {
  #pragma unroll
  for (int off = 32; off > 0; off >>= 1) {
    a += __shfl_xor(a, off);
    b += __shfl_xor(b, off);
  }
  __shared__ float2 red[4];
  int wv = threadIdx.x >> 6;
  if ((threadIdx.x & 63) == 0) red[wv] = make_float2(a, b);
  __syncthreads();
  float2 r0 = red[0], r1 = red[1], r2 = red[2], r3 = red[3];
  return make_float2(r0.x + r1.x + r2.x + r3.x, r0.y + r1.y + r2.y + r3.y);
}

// ---------------- merged = [rmsnorm(h_prev), rmsnorm(tok)] ----------------
__global__ __launch_bounds__(256) void merge_rms(const float* __restrict__ hprev,
                                                 const float* __restrict__ embed,
                                                 const int* __restrict__ tok,
                                                 f16* __restrict__ merged, int koff,
                                                 int hsel) {
  int r = blockIdx.x;
  int b = r / NPOS, t = r - b * NPOS;
  int tid = threadIdx.x;
  const float* hrow = (hsel >= 0)
      ? embed + (long)tok[b * 512 + t + hsel] * DMODEL
      : hprev + (long)r * DMODEL;
  float4 hv = ((const float4*)hrow)[tid];
  float4 tv = ((const float4*)(embed + (long)tok[b * 512 + t + koff] * DMODEL))[tid];
  float sh = hv.x * hv.x + hv.y * hv.y + hv.z * hv.z + hv.w * hv.w;
  float st = tv.x * tv.x + tv.y * tv.y + tv.z * tv.z + tv.w * tv.w;
  float2 tot = block_reduce2(sh, st);
  float ih = 1.0f / sqrtf(tot.x * (1.0f / DMODEL) + 1e-8f);
  float it = 1.0f / sqrtf(tot.y * (1.0f / DMODEL) + 1e-8f);
  f16x4 oh = {(f16)(hv.x * ih), (f16)(hv.y * ih), (f16)(hv.z * ih), (f16)(hv.w * ih)};
  f16x4 ot = {(f16)(tv.x * it), (f16)(tv.y * it), (f16)(tv.z * it), (f16)(tv.w * it)};
  *(f16x4*)(merged + (long)r * 2048 + tid * 4) = oh;
  *(f16x4*)(merged + (long)r * 2048 + 1024 + tid * 4) = ot;
}

// ---------------- y = LN(x + res) * g + b ----------------
__global__ __launch_bounds__(256) void add_ln(const float* __restrict__ x,
                                              const float* __restrict__ res,
                                              const float* __restrict__ g,
                                              const float* __restrict__ bb,
                                              float* __restrict__ yf,
                                              f16* __restrict__ yh) {
  int r = blockIdx.x, tid = threadIdx.x;
  float4 a = ((const float4*)(x + (long)r * DMODEL))[tid];
  float4 c = ((const float4*)(res + (long)r * DMODEL))[tid];
  a.x += c.x; a.y += c.y; a.z += c.z; a.w += c.w;
  float s  = a.x + a.y + a.z + a.w;
  float ss = a.x * a.x + a.y * a.y + a.z * a.z + a.w * a.w;
  float2 tot = block_reduce2(s, ss);
  float mean = tot.x * (1.0f / DMODEL);
  float var  = tot.y * (1.0f / DMODEL) - mean * mean;
  float inv  = 1.0f / sqrtf(var + 1e-5f);
  float4 gv = ((const float4*)g)[tid];
  float4 bv = ((const float4*)bb)[tid];
  float y0 = (a.x - mean) * inv * gv.x + bv.x;
  float y1 = (a.y - mean) * inv * gv.y + bv.y;
  float y2 = (a.z - mean) * inv * gv.z + bv.z;
  float y3 = (a.w - mean) * inv * gv.w + bv.w;
  float4 o = {y0, y1, y2, y3};
  ((float4*)(yf + (long)r * DMODEL))[tid] = o;
  f16x4 oh = {(f16)y0, (f16)y1, (f16)y2, (f16)y3};
  *(f16x4*)(yh + (long)r * DMODEL + tid * 4) = oh;
}

// ---------------- small GEMM: 64x64 tile, 3-buffer depth-2 prefetch ----------------
template <int HAS_BIAS, int RELU, int WF32, int WF16, int MASK>
__global__ __launch_bounds__(256) void gemm_sm(const f16* __restrict__ A,
                                               const f16* __restrict__ B,
                                               const float* __restrict__ bias,
                                               float* __restrict__ Cf,
                                               f16* __restrict__ Ch,
                                               int K, int N, long ldc, long coff,
                                               int mval, long zsA, long zsB, long zsC) {
  __shared__ __align__(16) f16 sA[3][2048];
  __shared__ __align__(16) f16 sB[3][2048];
  const int tid  = threadIdx.x;
  const int lane = tid & 63, wv = tid >> 6;
  const int wm = wv >> 1, wn = wv & 1;
  const int bm = blockIdx.y, bn = blockIdx.x;
  const int lr = lane & 15, lk = lane >> 4;

  A += (long)blockIdx.z * zsA;
  B += (long)blockIdx.z * zsB;
  Ch += (long)blockIdx.z * zsC;

  const f16* gA = A + ((long)(bm * 64 + (tid >> 2))) * K + (tid & 3) * 8;
  const f16* gB = B + ((long)(bn * 64 + (tid >> 2))) * K + (tid & 3) * 8;

  const int aoff = (wm * 32 + lr) * 32 + lk * 8;
  const int boff = (wn * 32 + lr) * 32 + lk * 8;

  f32x4 acc[2][2] = {};

#define SSTAGE(buf, kt)                                \
  gld_lds16(gA + (long)(kt) * 32, &sA[buf][tid * 8]);  \
  gld_lds16(gB + (long)(kt) * 32, &sB[buf][tid * 8]);

  const int nk = K >> 5;
  SSTAGE(0, 0);
  SSTAGE(1, 1);

  int cur = 0, stg = 2;
  for (int kt = 0; kt < nk; ++kt) {
    if (kt + 1 < nk) { VM2; } else { VM0; }
    BAR;
    if (kt + 2 < nk) { SSTAGE(stg, kt + 2); }
    f16x8 af0 = *(const f16x8*)&sA[cur][aoff];
    f16x8 af1 = *(const f16x8*)&sA[cur][aoff + 512];
    f16x8 bf0 = *(const f16x8*)&sB[cur][boff];
    f16x8 bf1 = *(const f16x8*)&sB[cur][boff + 512];
    acc[0][0] = MFMA16(af0, bf0, acc[0][0]);
    acc[0][1] = MFMA16(af0, bf1, acc[0][1]);
    acc[1][0] = MFMA16(af1, bf0, acc[1][0]);
    acc[1][1] = MFMA16(af1, bf1, acc[1][1]);
    cur = cur == 2 ? 0 : cur + 1;
    stg = stg == 2 ? 0 : stg + 1;
  }
#undef SSTAGE

  const int row0 = bm * 64 + wm * 32 + lk * 4;
  const int col0 = bn * 64 + wn * 32 + lr;
  #pragma unroll
  for (int mi = 0; mi < 2; ++mi) {
    #pragma unroll
    for (int ni = 0; ni < 2; ++ni) {
      int col = col0 + ni * 16;
      float bs = HAS_BIAS ? bias[col] : 0.0f;
      #pragma unroll
      for (int rg = 0; rg < 4; ++rg) {
        int row = row0 + mi * 16 + rg;
        if (!MASK || row < mval) {
          float v = acc[mi][ni][rg] + bs;
          if (RELU) v = v > 0.0f ? v : 0.0f;
          if (WF32) Cf[(long)row * ldc + coff + col] = v;
          if (WF16) Ch[(long)row * N + col] = (f16)v;
        }
      }
    }
  }
}

// ---------------- mega logits GEMM: M=6144 (3 heads), 256x256 tile ----------------
// BK=32, 4-slot ring (128 KiB LDS), deep prefetch: stage tile t+3 at iter t.
// Ledger: prologue stages tiles 0-2 (12 loads). ph1 of iter t issues A(t+3)
// (2 loads, <=14 outstanding) then vmcnt(10): retires A(t),B(t) exactly,
// leaves 5 newer pairs in flight (~3 K-tiles ~ 1200+ cyc -> covers L3 latency).
// ph2 issues B(t+3), no wait. Slot (t+3)&3 = (t-1)&3: last read before iter
// t-1's end-barrier -> race-free. 2 barriers/iter.
__global__ __launch_bounds__(512, 2) void gemm256x(const f16* __restrict__ A,
                                                   const f16* __restrict__ B,
                                                   float* __restrict__ C) {
  __shared__ __align__(16) f16 sA[4][8192];
  __shared__ __align__(16) f16 sB[4][8192];
  const int K = 1024;
  const int tid = threadIdx.x;
  const int lane = tid & 63;
  const int wv = tid >> 6;
  const int wm = wv >> 2, wn = wv & 3;
  const int lr = lane & 15, lk = lane >> 4;

  // A-resident XCD swizzle: 3000 blocks = 8 XCDs x 375. Each XCD owns 3 bm
  // values (1.5 MB A slice, L2-resident); B streams from L3.
  const int flat = blockIdx.y * 125 + blockIdx.x;
  const int xcd = flat & 7, idx = flat >> 3;
  const int bm = xcd * 3 + (idx % 3);
  const int bn = idx / 3;

  const int srow = tid >> 2;          // 0..127
  const int scol = (tid & 3) * 8;
  const f16* gA = A + (long)(bm * 256 + srow) * K + scol;
  const f16* gB = B + (long)(bn * 256 + srow) * K + scol;
  const long rstep = 128L * (long)K;

  const int aoff = (wm * 128 + lr) * 32 + lk * 8;  // + mi*512
  const int boff = (wn * 64  + lr) * 32 + lk * 8;  // + ni*512

  f32x4 acc[8][4] = {};

#define STG_A(s, kt)                                            \
  gld_lds16(gA + (long)(kt) * 32, &sA[s][tid * 8]);             \
  gld_lds16(gA + (long)(kt) * 32 + rstep, &sA[s][tid * 8 + 4096]);
#define STG_B(s, kt)                                            \
  gld_lds16(gB + (long)(kt) * 32, &sB[s][tid * 8]);             \
  gld_lds16(gB + (long)(kt) * 32 + rstep, &sB[s][tid * 8 + 4096]);

  // prologue: tiles 0,1,2
  STG_A(0, 0); STG_B(0, 0);
  STG_A(1, 1); STG_B(1, 1);
  STG_A(2, 2); STG_B(2, 2);

  const int nt = 32;  // K / 32
  for (int t = 0; t < nt; ++t) {
    const int cur = t & 3, pre = (t + 3) & 3;
    const int kt = (t + 3 < nt) ? (t + 3) : 0;  // wrap keeps ledger uniform
    f16x8 af[8], bf[4];

    // phase 1: n-frags 0-1
    STG_A(pre, kt);
    VM10;
    BAR;
    #pragma unroll
    for (int mi = 0; mi < 8; ++mi) af[mi] = *(const f16x8*)&sA[cur][aoff + mi * 512];
    bf[0] = *(const f16x8*)&sB[cur][boff];
    bf[1] = *(const f16x8*)&sB[cur][boff + 512];
    __builtin_amdgcn_s_setprio(1);
    #pragma unroll
    for (int mi = 0; mi < 8; ++mi) {
      acc[mi][0] = MFMA16(af[mi], bf[0], acc[mi][0]);
      acc[mi][1] = MFMA16(af[mi], bf[1], acc[mi][1]);
    }
    __builtin_amdgcn_s_setprio(0);

    // phase 2: n-frags 2-3
    STG_B(pre, kt);
    bf[2] = *(const f16x8*)&sB[cur][boff + 1024];
    bf[3] = *(const f16x8*)&sB[cur][boff + 1536];
    __builtin_amdgcn_s_setprio(1);
    #pragma unroll
    for (int mi = 0; mi < 8; ++mi) {
      acc[mi][2] = MFMA16(af[mi], bf[2], acc[mi][2]);
      acc[mi][3] = MFMA16(af[mi], bf[3], acc[mi][3]);
    }
    __builtin_amdgcn_s_setprio(0);
    BAR;  // end: all waves done reading slot `cur` before it is restaged
  }
  VM0;

  // epilogue: head = bm>>3 (blocks never straddle heads: 2048 % 256 == 0)
  const int head = bm >> 3;
  const long coff = (long)head * 32000;
  const int row0 = (bm & 7) * 256 + wm * 128 + lk * 4;
  const int col0 = bn * 256 + wn * 64 + lr;
  #pragma unroll
  for (int mi = 0; mi < 8; ++mi) {
    #pragma unroll
    for (int ni = 0; ni < 4; ++ni) {
      int col = col0 + ni * 16;
      #pragma unroll
      for (int rg = 0; rg < 4; ++rg) {
        int row = row0 + mi * 16 + rg;
        if (row < MROWS) C[(long)row * 96000 + coff + col] = acc[mi][ni][rg];
      }
    }
  }
#undef STG_A
#undef STG_B
}

// ---------------- host-side orchestration ----------------
extern "C" void kernel_launch(void* const* d_in, const int* in_sizes, int n_in,
                              void* d_out, int out_size, void* d_ws, size_t ws_size,
                              hipStream_t stream) {
  const int*   tok   = (const int*)d_in[0];
  const float* embed = (const float*)d_in[1];
  auto P = [&](int k, int j) { return (const float*)d_in[2 + k * 14 + j]; };
  float* out = (float*)d_out;

  char* w = (char*)d_ws;
  auto alloc = [&](size_t bytes) { char* p = w; w += bytes; return p; };
  const size_t MM = (size_t)1024 * 1024;

  f16* embed_h = (f16*)alloc((size_t)32000 * 1024 * 2);
  f16* Wo_all  = (f16*)alloc(3 * MM * 2);
  f16* Wvo_all = (f16*)alloc(3 * MM * 2);
  f16 *Wm_h[3], *W1_h[3], *W2_h[3];
  for (int k = 0; k < 3; ++k) {
    Wm_h[k]  = (f16*)alloc((size_t)1024 * 2048 * 2);
    W1_h[k]  = (f16*)alloc((size_t)2048 * 1024 * 2);
    W2_h[k]  = (f16*)alloc((size_t)1024 * 2048 * 2);
  }
  float* hprev  = (float*)alloc((size_t)MPAD * 1024 * 4);
  f16*   h_all  = (f16*)alloc((size_t)3 * MPAD * 1024 * 2);  // h for 3 heads
  f16*   merged = (f16*)alloc((size_t)MPAD * 2048 * 2);
  float* xf     = (float*)alloc((size_t)MPAD * 1024 * 4);
  f16*   xh     = (f16*)alloc((size_t)MPAD * 1024 * 2);
  f16*   ff1    = (f16*)alloc((size_t)MPAD * 2048 * 2);
  float* t1     = (float*)alloc((size_t)MPAD * 1024 * 4);
  float* bvo    = (float*)alloc(3 * 1024 * 4);
  f16* WvT_all = merged;  // scratch overlay (merged written later, stream-ordered)

  // ---- prep ----
  conv_f32_f16<<<16000, 256, 0, stream>>>(embed, embed_h, (long)32000 * 1024);

  ConvArgs ca;
  for (int k = 0; k < 3; ++k) {
    ca.s[k*4+0] = P(k, 0); ca.d[k*4+0] = Wm_h[k];        ca.n[k*4+0] = (long)1024 * 2048;
    ca.s[k*4+1] = P(k, 4); ca.d[k*4+1] = Wo_all + k*MM;  ca.n[k*4+1] = (long)1024 * 1024;
    ca.s[k*4+2] = P(k, 6); ca.d[k*4+2] = W1_h[k];        ca.n[k*4+2] = (long)2048 * 1024;
    ca.s[k*4+3] = P(k, 8); ca.d[k*4+3] = W2_h[k];        ca.n[k*4+3] = (long)1024 * 2048;
  }
  conv_many<<<dim3(1024, 12), 256, 0, stream>>>(ca);

  TpArgs ta;
  for (int k = 0; k < 3; ++k) { ta.s[k] = P(k, 2); ta.d[k] = WvT_all + k * MM; }
  transpose3<<<dim3(32, 32, 3), 256, 0, stream>>>(ta);

  gemm_sm<0, 0, 0, 1, 0><<<dim3(16, 16, 3), 256, 0, stream>>>(
      Wo_all, WvT_all, nullptr, nullptr, Wvo_all, 1024, 1024, 1024L, 0L, 1024,
      (long)MM, (long)MM, (long)MM);

  BvoArgs ba;
  for (int k = 0; k < 3; ++k) {
    ba.Wo[k] = P(k, 4); ba.bv[k] = P(k, 3); ba.bo[k] = P(k, 5); ba.out[k] = bvo + k * 1024;
  }
  make_bvo3<<<dim3(1024, 3), 64, 0, stream>>>(ba);

  // ---- 3 encoder chains (logits deferred to one mega GEMM) ----
  for (int k = 0; k < 3; ++k) {
    merge_rms<<<MROWS, 256, 0, stream>>>(hprev, embed, tok, merged, k + 1,
                                         k == 0 ? 0 : -1);
    gemm_sm<1, 0, 1, 1, 0><<<dim3(16, 32), 256, 0, stream>>>(
        merged, Wm_h[k], P(k, 1), xf, xh, 2048, 1024, 1024L, 0L, MROWS, 0L, 0L, 0L);
    gemm_sm<1, 0, 1, 0, 0><<<dim3(16, 32), 256, 0, stream>>>(
        xh, Wvo_all + k * MM, bvo + k * 1024, t1, nullptr, 1024, 1024, 1024L, 0L,
        MROWS, 0L, 0L, 0L);
    add_ln<<<MROWS, 256, 0, stream>>>(xf, t1, P(k, 10), P(k, 11), xf, xh);
    gemm_sm<1, 1, 0, 1, 0><<<dim3(32, 32), 256, 0, stream>>>(
        xh, W1_h[k], P(k, 7), nullptr, ff1, 1024, 2048, 2048L, 0L, MROWS, 0L, 0L, 0L);
    gemm_sm<1, 0, 1, 0, 0><<<dim3(16, 32), 256, 0, stream>>>(
        ff1, W2_h[k], P(k, 9), t1, nullptr, 2048, 1024, 1024L, 0L, MROWS, 0L, 0L, 0L);
    add_ln<<<MROWS, 256, 0, stream>>>(xf, t1, P(k, 12), P(k, 13), hprev,
                                      h_all + (size_t)k * MPAD * 1024);
  }

  // ---- one mega logits GEMM: [3*2048, 1024] @ embed^T -> out[:, :, k, :] ----
  gemm256x<<<dim3(125, 24), 512, 0, stream>>>(h_all, embed_h, out);
}

// Round 6
// 1004.242 us; speedup vs baseline: 1.4013x; 1.0324x over previous
//
#include <hip/hip_runtime.h>

// SimpleMTP: 3 sequential MTP heads on MI355X.
// f16 MFMA everywhere heavy; f32 residual/norms.
// Logits: ONE 256x256 GEMM (M=6144), BK=32 4-slot ring, vmcnt(10) deep
//   prefetch, XCD A-resident swizzle, LDS chunk-XOR swizzle (bank-conflict
//   free, both-sides), nontemporal f32 stores (keep embed_h L3-resident).
// Small GEMMs: 64x64, 3-buffer depth-2 prefetch.
// Wv/Wo fused into Wvo = Wo@Wv (precomputed per call).

#define NPOS   509
#define MROWS  2036
#define MPAD   2048
#define DMODEL 1024

typedef _Float16 f16;
typedef _Float16 f16x8 __attribute__((ext_vector_type(8)));
typedef _Float16 f16x4 __attribute__((ext_vector_type(4)));
typedef float    f32x4 __attribute__((ext_vector_type(4)));

#define MFMA16(a, b, c) __builtin_amdgcn_mfma_f32_16x16x32_f16(a, b, c, 0, 0, 0)
#define VM0  asm volatile("s_waitcnt vmcnt(0)" ::: "memory")
#define VM2  asm volatile("s_waitcnt vmcnt(2)" ::: "memory")
#define VM10 asm volatile("s_waitcnt vmcnt(10)" ::: "memory")
#define BAR  asm volatile("s_barrier" ::: "memory")

__device__ __forceinline__ void gld_lds16(const void* g, void* l) {
  __builtin_amdgcn_global_load_lds(
      (const __attribute__((address_space(1))) void*)g,
      (__attribute__((address_space(3))) void*)l, 16, 0, 0);
}

// ---------------- f32 -> f16 convert: embed ----------------
__global__ __launch_bounds__(256) void conv_f32_f16(const float* __restrict__ src,
                                                    f16* __restrict__ dst, long n) {
  long i = ((long)blockIdx.x * 256 + threadIdx.x) * 8;
  if (i + 8 <= n) {
    float4 a = *(const float4*)(src + i);
    float4 b = *(const float4*)(src + i + 4);
    f16x8 o = {(f16)a.x, (f16)a.y, (f16)a.z, (f16)a.w,
               (f16)b.x, (f16)b.y, (f16)b.z, (f16)b.w};
    *(f16x8*)(dst + i) = o;
  }
}

// ---------------- batched weight conversion (12 tensors) ----------------
struct ConvArgs { const float* s[12]; f16* d[12]; long n[12]; };
__global__ __launch_bounds__(256) void conv_many(ConvArgs a) {
  int t = blockIdx.y;
  long i = ((long)blockIdx.x * 256 + threadIdx.x) * 8;
  if (i + 8 <= a.n[t]) {
    const float* src = a.s[t];
    float4 x = *(const float4*)(src + i);
    float4 y = *(const float4*)(src + i + 4);
    f16x8 o = {(f16)x.x, (f16)x.y, (f16)x.z, (f16)x.w,
               (f16)y.x, (f16)y.y, (f16)y.z, (f16)y.w};
    *(f16x8*)(a.d[t] + i) = o;
  }
}

// ---------------- batched 1024x1024 transpose f32->f16 (Wv -> WvT) ----------------
struct TpArgs { const float* s[3]; f16* d[3]; };
__global__ __launch_bounds__(256) void transpose3(TpArgs a) {
  __shared__ float t[32][33];
  int h = blockIdx.z;
  int bx = blockIdx.x * 32, by = blockIdx.y * 32;
  int tx = threadIdx.x & 31, ty = threadIdx.x >> 5;
  const float* src = a.s[h];
  f16* dst = a.d[h];
  #pragma unroll
  for (int r = 0; r < 32; r += 8)
    t[ty + r][tx] = src[(long)(by + ty + r) * 1024 + bx + tx];
  __syncthreads();
  #pragma unroll
  for (int r = 0; r < 32; r += 8)
    dst[(long)(bx + ty + r) * 1024 + by + tx] = (f16)t[tx][ty + r];
}

// ---------------- bvo = Wo @ bv + bo (batched over heads) ----------------
struct BvoArgs { const float* Wo[3]; const float* bv[3]; const float* bo[3]; float* out[3]; };
__global__ __launch_bounds__(64) void make_bvo3(BvoArgs a) {
  int h = blockIdx.y, r = blockIdx.x, l = threadIdx.x;
  const float* Wo = a.Wo[h];
  const float* bv = a.bv[h];
  float s = 0.0f;
  for (int k = l; k < 1024; k += 64) s += Wo[(long)r * 1024 + k] * bv[k];
  #pragma unroll
  for (int off = 32; off > 0; off >>= 1) s += __shfl_xor(s, off);
  if (l == 0) a.out[h][r] = s + a.bo[h][r];
}

__device__ __forceinline__ float2 block_reduce2(float a, float b) {
  #pragma unroll
  for (int off = 32; off > 0; off >>= 1) {
    a += __shfl_xor(a, off);
    b += __shfl_xor(b, off);
  }
  __shared__ float2 red[4];
  int wv = threadIdx.x >> 6;
  if ((threadIdx.x & 63) == 0) red[wv] = make_float2(a, b);
  __syncthreads();
  float2 r0 = red[0], r1 = red[1], r2 = red[2], r3 = red[3];
  return make_float2(r0.x + r1.x + r2.x + r3.x, r0.y + r1.y + r2.y + r3.y);
}

// ---------------- merged = [rmsnorm(h_prev), rmsnorm(tok)] ----------------
__global__ __launch_bounds__(256) void merge_rms(const float* __restrict__ hprev,
                                                 const float* __restrict__ embed,
                                                 const int* __restrict__ tok,
                                                 f16* __restrict__ merged, int koff,
                                                 int hsel) {
  int r = blockIdx.x;
  int b = r / NPOS, t = r - b * NPOS;
  int tid = threadIdx.x;
  const float* hrow = (hsel >= 0)
      ? embed + (long)tok[b * 512 + t + hsel] * DMODEL
      : hprev + (long)r * DMODEL;
  float4 hv = ((const float4*)hrow)[tid];
  float4 tv = ((const float4*)(embed + (long)tok[b * 512 + t + koff] * DMODEL))[tid];
  float sh = hv.x * hv.x + hv.y * hv.y + hv.z * hv.z + hv.w * hv.w;
  float st = tv.x * tv.x + tv.y * tv.y + tv.z * tv.z + tv.w * tv.w;
  float2 tot = block_reduce2(sh, st);
  float ih = 1.0f / sqrtf(tot.x * (1.0f / DMODEL) + 1e-8f);
  float it = 1.0f / sqrtf(tot.y * (1.0f / DMODEL) + 1e-8f);
  f16x4 oh = {(f16)(hv.x * ih), (f16)(hv.y * ih), (f16)(hv.z * ih), (f16)(hv.w * ih)};
  f16x4 ot = {(f16)(tv.x * it), (f16)(tv.y * it), (f16)(tv.z * it), (f16)(tv.w * it)};
  *(f16x4*)(merged + (long)r * 2048 + tid * 4) = oh;
  *(f16x4*)(merged + (long)r * 2048 + 1024 + tid * 4) = ot;
}

// ---------------- y = LN(x + res) * g + b ----------------
__global__ __launch_bounds__(256) void add_ln(const float* __restrict__ x,
                                              const float* __restrict__ res,
                                              const float* __restrict__ g,
                                              const float* __restrict__ bb,
                                              float* __restrict__ yf,
                                              f16* __restrict__ yh) {
  int r = blockIdx.x, tid = threadIdx.x;
  float4 a = ((const float4*)(x + (long)r * DMODEL))[tid];
  float4 c = ((const float4*)(res + (long)r * DMODEL))[tid];
  a.x += c.x; a.y += c.y; a.z += c.z; a.w += c.w;
  float s  = a.x + a.y + a.z + a.w;
  float ss = a.x * a.x + a.y * a.y + a.z * a.z + a.w * a.w;
  float2 tot = block_reduce2(s, ss);
  float mean = tot.x * (1.0f / DMODEL);
  float var  = tot.y * (1.0f / DMODEL) - mean * mean;
  float inv  = 1.0f / sqrtf(var + 1e-5f);
  float4 gv = ((const float4*)g)[tid];
  float4 bv = ((const float4*)bb)[tid];
  float y0 = (a.x - mean) * inv * gv.x + bv.x;
  float y1 = (a.y - mean) * inv * gv.y + bv.y;
  float y2 = (a.z - mean) * inv * gv.z + bv.z;
  float y3 = (a.w - mean) * inv * gv.w + bv.w;
  float4 o = {y0, y1, y2, y3};
  ((float4*)(yf + (long)r * DMODEL))[tid] = o;
  f16x4 oh = {(f16)y0, (f16)y1, (f16)y2, (f16)y3};
  *(f16x4*)(yh + (long)r * DMODEL + tid * 4) = oh;
}

// ---------------- small GEMM: 64x64 tile, 3-buffer depth-2 prefetch ----------------
template <int HAS_BIAS, int RELU, int WF32, int WF16, int MASK>
__global__ __launch_bounds__(256) void gemm_sm(const f16* __restrict__ A,
                                               const f16* __restrict__ B,
                                               const float* __restrict__ bias,
                                               float* __restrict__ Cf,
                                               f16* __restrict__ Ch,
                                               int K, int N, long ldc, long coff,
                                               int mval, long zsA, long zsB, long zsC) {
  __shared__ __align__(16) f16 sA[3][2048];
  __shared__ __align__(16) f16 sB[3][2048];
  const int tid  = threadIdx.x;
  const int lane = tid & 63, wv = tid >> 6;
  const int wm = wv >> 1, wn = wv & 1;
  const int bm = blockIdx.y, bn = blockIdx.x;
  const int lr = lane & 15, lk = lane >> 4;

  A += (long)blockIdx.z * zsA;
  B += (long)blockIdx.z * zsB;
  Ch += (long)blockIdx.z * zsC;

  const f16* gA = A + ((long)(bm * 64 + (tid >> 2))) * K + (tid & 3) * 8;
  const f16* gB = B + ((long)(bn * 64 + (tid >> 2))) * K + (tid & 3) * 8;

  const int aoff = (wm * 32 + lr) * 32 + lk * 8;
  const int boff = (wn * 32 + lr) * 32 + lk * 8;

  f32x4 acc[2][2] = {};

#define SSTAGE(buf, kt)                                \
  gld_lds16(gA + (long)(kt) * 32, &sA[buf][tid * 8]);  \
  gld_lds16(gB + (long)(kt) * 32, &sB[buf][tid * 8]);

  const int nk = K >> 5;
  SSTAGE(0, 0);
  SSTAGE(1, 1);

  int cur = 0, stg = 2;
  for (int kt = 0; kt < nk; ++kt) {
    if (kt + 1 < nk) { VM2; } else { VM0; }
    BAR;
    if (kt + 2 < nk) { SSTAGE(stg, kt + 2); }
    f16x8 af0 = *(const f16x8*)&sA[cur][aoff];
    f16x8 af1 = *(const f16x8*)&sA[cur][aoff + 512];
    f16x8 bf0 = *(const f16x8*)&sB[cur][boff];
    f16x8 bf1 = *(const f16x8*)&sB[cur][boff + 512];
    acc[0][0] = MFMA16(af0, bf0, acc[0][0]);
    acc[0][1] = MFMA16(af0, bf1, acc[0][1]);
    acc[1][0] = MFMA16(af1, bf0, acc[1][0]);
    acc[1][1] = MFMA16(af1, bf1, acc[1][1]);
    cur = cur == 2 ? 0 : cur + 1;
    stg = stg == 2 ? 0 : stg + 1;
  }
#undef SSTAGE

  const int row0 = bm * 64 + wm * 32 + lk * 4;
  const int col0 = bn * 64 + wn * 32 + lr;
  #pragma unroll
  for (int mi = 0; mi < 2; ++mi) {
    #pragma unroll
    for (int ni = 0; ni < 2; ++ni) {
      int col = col0 + ni * 16;
      float bs = HAS_BIAS ? bias[col] : 0.0f;
      #pragma unroll
      for (int rg = 0; rg < 4; ++rg) {
        int row = row0 + mi * 16 + rg;
        if (!MASK || row < mval) {
          float v = acc[mi][ni][rg] + bs;
          if (RELU) v = v > 0.0f ? v : 0.0f;
          if (WF32) Cf[(long)row * ldc + coff + col] = v;
          if (WF16) Ch[(long)row * N + col] = (f16)v;
        }
      }
    }
  }
}

// ---------------- mega logits GEMM: M=6144 (3 heads), 256x256 tile ----------------
// BK=32, 4-slot ring, vmcnt(10) deep prefetch (see round-5 ledger).
// LDS chunk-XOR swizzle: LDS[row][chunk] holds global chunk (chunk^((row>>1)&3)).
//   Staging: fold XOR into per-thread global source (LDS dest stays linear).
//   Reads: XOR is lane-constant ((lr>>1)&3 -- wm*128/wn*64/mi*16 keep bits 1-2),
//   folded into aoff/boff. Bank-groups: g=(4r+c') mod 8 covers all 8 over rows
//   0-7 -> 2 accesses/group = free 2-way level.
// Output via nontemporal stores: 764 MB write stream must not evict embed_h
// (64 MB) from L3; B-rereads (24x) become L3 hits.
__global__ __launch_bounds__(512, 2) void gemm256x(const f16* __restrict__ A,
                                                   const f16* __restrict__ B,
                                                   float* __restrict__ C) {
  __shared__ __align__(16) f16 sA[4][8192];
  __shared__ __align__(16) f16 sB[4][8192];
  const int K = 1024;
  const int tid = threadIdx.x;
  const int lane = tid & 63;
  const int wv = tid >> 6;
  const int wm = wv >> 2, wn = wv & 3;
  const int lr = lane & 15, lk = lane >> 4;

  // A-resident XCD swizzle: 3000 blocks = 8 XCDs x 375; each XCD owns 3 bm.
  const int flat = blockIdx.y * 125 + blockIdx.x;
  const int xcd = flat & 7, idx = flat >> 3;
  const int bm = xcd * 3 + (idx % 3);
  const int bn = idx / 3;

  const int srow = tid >> 2;                         // 0..127
  const int schunk = (tid & 3) ^ ((tid >> 3) & 3);   // pre-swizzled source chunk
  const f16* gA = A + (long)(bm * 256 + srow) * K + schunk * 8;
  const f16* gB = B + (long)(bn * 256 + srow) * K + schunk * 8;
  const long rstep = 128L * (long)K;

  const int swz = ((lr >> 1) & 3) << 3;              // elem-XOR for frag reads
  const int aoff = (((wm * 128 + lr) * 32) + lk * 8) ^ swz;  // + mi*512
  const int boff = (((wn * 64  + lr) * 32) + lk * 8) ^ swz;  // + ni*512

  f32x4 acc[8][4] = {};

#define STG_A(s, kt)                                            \
  gld_lds16(gA + (long)(kt) * 32, &sA[s][tid * 8]);             \
  gld_lds16(gA + (long)(kt) * 32 + rstep, &sA[s][tid * 8 + 4096]);
#define STG_B(s, kt)                                            \
  gld_lds16(gB + (long)(kt) * 32, &sB[s][tid * 8]);             \
  gld_lds16(gB + (long)(kt) * 32 + rstep, &sB[s][tid * 8 + 4096]);

  // prologue: tiles 0,1,2
  STG_A(0, 0); STG_B(0, 0);
  STG_A(1, 1); STG_B(1, 1);
  STG_A(2, 2); STG_B(2, 2);

  const int nt = 32;  // K / 32
  for (int t = 0; t < nt; ++t) {
    const int cur = t & 3, pre = (t + 3) & 3;
    const int kt = (t + 3 < nt) ? (t + 3) : 0;  // wrap keeps ledger uniform
    f16x8 af[8], bf[4];

    // phase 1: n-frags 0-1
    STG_A(pre, kt);
    VM10;
    BAR;
    #pragma unroll
    for (int mi = 0; mi < 8; ++mi) af[mi] = *(const f16x8*)&sA[cur][aoff + mi * 512];
    bf[0] = *(const f16x8*)&sB[cur][boff];
    bf[1] = *(const f16x8*)&sB[cur][boff + 512];
    __builtin_amdgcn_s_setprio(1);
    #pragma unroll
    for (int mi = 0; mi < 8; ++mi) {
      acc[mi][0] = MFMA16(af[mi], bf[0], acc[mi][0]);
      acc[mi][1] = MFMA16(af[mi], bf[1], acc[mi][1]);
    }
    __builtin_amdgcn_s_setprio(0);

    // phase 2: n-frags 2-3
    STG_B(pre, kt);
    bf[2] = *(const f16x8*)&sB[cur][boff + 1024];
    bf[3] = *(const f16x8*)&sB[cur][boff + 1536];
    __builtin_amdgcn_s_setprio(1);
    #pragma unroll
    for (int mi = 0; mi < 8; ++mi) {
      acc[mi][2] = MFMA16(af[mi], bf[2], acc[mi][2]);
      acc[mi][3] = MFMA16(af[mi], bf[3], acc[mi][3]);
    }
    __builtin_amdgcn_s_setprio(0);
    BAR;  // all waves done reading slot `cur` before it is restaged
  }
  VM0;

  // epilogue: head = bm>>3; nontemporal stores (don't pollute L3)
  const int head = bm >> 3;
  const long coff = (long)head * 32000;
  const int row0 = (bm & 7) * 256 + wm * 128 + lk * 4;
  const int col0 = bn * 256 + wn * 64 + lr;
  #pragma unroll
  for (int mi = 0; mi < 8; ++mi) {
    #pragma unroll
    for (int ni = 0; ni < 4; ++ni) {
      int col = col0 + ni * 16;
      #pragma unroll
      for (int rg = 0; rg < 4; ++rg) {
        int row = row0 + mi * 16 + rg;
        if (row < MROWS)
          __builtin_nontemporal_store(acc[mi][ni][rg],
                                      &C[(long)row * 96000 + coff + col]);
      }
    }
  }
#undef STG_A
#undef STG_B
}

// ---------------- host-side orchestration ----------------
extern "C" void kernel_launch(void* const* d_in, const int* in_sizes, int n_in,
                              void* d_out, int out_size, void* d_ws, size_t ws_size,
                              hipStream_t stream) {
  const int*   tok   = (const int*)d_in[0];
  const float* embed = (const float*)d_in[1];
  auto P = [&](int k, int j) { return (const float*)d_in[2 + k * 14 + j]; };
  float* out = (float*)d_out;

  char* w = (char*)d_ws;
  auto alloc = [&](size_t bytes) { char* p = w; w += bytes; return p; };
  const size_t MM = (size_t)1024 * 1024;

  f16* embed_h = (f16*)alloc((size_t)32000 * 1024 * 2);
  f16* Wo_all  = (f16*)alloc(3 * MM * 2);
  f16* Wvo_all = (f16*)alloc(3 * MM * 2);
  f16 *Wm_h[3], *W1_h[3], *W2_h[3];
  for (int k = 0; k < 3; ++k) {
    Wm_h[k]  = (f16*)alloc((size_t)1024 * 2048 * 2);
    W1_h[k]  = (f16*)alloc((size_t)2048 * 1024 * 2);
    W2_h[k]  = (f16*)alloc((size_t)1024 * 2048 * 2);
  }
  float* hprev  = (float*)alloc((size_t)MPAD * 1024 * 4);
  f16*   h_all  = (f16*)alloc((size_t)3 * MPAD * 1024 * 2);
  f16*   merged = (f16*)alloc((size_t)MPAD * 2048 * 2);
  float* xf     = (float*)alloc((size_t)MPAD * 1024 * 4);
  f16*   xh     = (f16*)alloc((size_t)MPAD * 1024 * 2);
  f16*   ff1    = (f16*)alloc((size_t)MPAD * 2048 * 2);
  float* t1     = (float*)alloc((size_t)MPAD * 1024 * 4);
  float* bvo    = (float*)alloc(3 * 1024 * 4);
  f16* WvT_all = merged;  // scratch overlay (merged written later, stream-ordered)

  // ---- prep ----
  conv_f32_f16<<<16000, 256, 0, stream>>>(embed, embed_h, (long)32000 * 1024);

  ConvArgs ca;
  for (int k = 0; k < 3; ++k) {
    ca.s[k*4+0] = P(k, 0); ca.d[k*4+0] = Wm_h[k];        ca.n[k*4+0] = (long)1024 * 2048;
    ca.s[k*4+1] = P(k, 4); ca.d[k*4+1] = Wo_all + k*MM;  ca.n[k*4+1] = (long)1024 * 1024;
    ca.s[k*4+2] = P(k, 6); ca.d[k*4+2] = W1_h[k];        ca.n[k*4+2] = (long)2048 * 1024;
    ca.s[k*4+3] = P(k, 8); ca.d[k*4+3] = W2_h[k];        ca.n[k*4+3] = (long)1024 * 2048;
  }
  conv_many<<<dim3(1024, 12), 256, 0, stream>>>(ca);

  TpArgs ta;
  for (int k = 0; k < 3; ++k) { ta.s[k] = P(k, 2); ta.d[k] = WvT_all + k * MM; }
  transpose3<<<dim3(32, 32, 3), 256, 0, stream>>>(ta);

  gemm_sm<0, 0, 0, 1, 0><<<dim3(16, 16, 3), 256, 0, stream>>>(
      Wo_all, WvT_all, nullptr, nullptr, Wvo_all, 1024, 1024, 1024L, 0L, 1024,
      (long)MM, (long)MM, (long)MM);

  BvoArgs ba;
  for (int k = 0; k < 3; ++k) {
    ba.Wo[k] = P(k, 4); ba.bv[k] = P(k, 3); ba.bo[k] = P(k, 5); ba.out[k] = bvo + k * 1024;
  }
  make_bvo3<<<dim3(1024, 3), 64, 0, stream>>>(ba);

  // ---- 3 encoder chains (logits deferred to one mega GEMM) ----
  for (int k = 0; k < 3; ++k) {
    merge_rms<<<MROWS, 256, 0, stream>>>(hprev, embed, tok, merged, k + 1,
                                         k == 0 ? 0 : -1);
    gemm_sm<1, 0, 1, 1, 0><<<dim3(16, 32), 256, 0, stream>>>(
        merged, Wm_h[k], P(k, 1), xf, xh, 2048, 1024, 1024L, 0L, MROWS, 0L, 0L, 0L);
    gemm_sm<1, 0, 1, 0, 0><<<dim3(16, 32), 256, 0, stream>>>(
        xh, Wvo_all + k * MM, bvo + k * 1024, t1, nullptr, 1024, 1024, 1024L, 0L,
        MROWS, 0L, 0L, 0L);
    add_ln<<<MROWS, 256, 0, stream>>>(xf, t1, P(k, 10), P(k, 11), xf, xh);
    gemm_sm<1, 1, 0, 1, 0><<<dim3(32, 32), 256, 0, stream>>>(
        xh, W1_h[k], P(k, 7), nullptr, ff1, 1024, 2048, 2048L, 0L, MROWS, 0L, 0L, 0L);
    gemm_sm<1, 0, 1, 0, 0><<<dim3(16, 32), 256, 0, stream>>>(
        ff1, W2_h[k], P(k, 9), t1, nullptr, 2048, 1024, 1024L, 0L, MROWS, 0L, 0L, 0L);
    add_ln<<<MROWS, 256, 0, stream>>>(xf, t1, P(k, 12), P(k, 13), hprev,
                                      h_all + (size_t)k * MPAD * 1024);
  }

  // ---- one mega logits GEMM ----
  gemm256x<<<dim3(125, 24), 512, 0, stream>>>(h_all, embed_h, out);
}

// Round 9
// 992.604 us; speedup vs baseline: 1.4177x; 1.0117x over previous
//
#include <hip/hip_runtime.h>

// SimpleMTP: 3 sequential MTP heads on MI355X.
// f16 MFMA everywhere heavy; f32 residual/norms.
// Logits: ONE 256x256 GEMM (M=6144), BK=64, 2 dbuf, 4-phase x 2-barrier
//   fine interleave (m201 template), vmcnt(4)@P2/P4 counted waits,
//   XCD A-resident swizzle, LDS chunk-XOR swizzle (0 conflicts), plain stores.
// Small GEMMs: 64x64, 3-buffer depth-2 prefetch.
// Wv/Wo fused into Wvo = Wo@Wv (precomputed per call).

#define NPOS   509
#define MROWS  2036
#define MPAD   2048
#define DMODEL 1024

typedef _Float16 f16;
typedef _Float16 f16x8 __attribute__((ext_vector_type(8)));
typedef _Float16 f16x4 __attribute__((ext_vector_type(4)));
typedef float    f32x4 __attribute__((ext_vector_type(4)));

#define MFMA16(a, b, c) __builtin_amdgcn_mfma_f32_16x16x32_f16(a, b, c, 0, 0, 0)
#define VM0   asm volatile("s_waitcnt vmcnt(0)" ::: "memory")
#define VM2   asm volatile("s_waitcnt vmcnt(2)" ::: "memory")
#define VM4   asm volatile("s_waitcnt vmcnt(4)" ::: "memory")
#define LGKM0 asm volatile("s_waitcnt lgkmcnt(0)" ::: "memory")
#define SCHED0 __builtin_amdgcn_sched_barrier(0)
#define BAR   asm volatile("s_barrier" ::: "memory")

__device__ __forceinline__ void gld_lds16(const void* g, void* l) {
  __builtin_amdgcn_global_load_lds(
      (const __attribute__((address_space(1))) void*)g,
      (__attribute__((address_space(3))) void*)l, 16, 0, 0);
}

// ---------------- f32 -> f16 convert: embed ----------------
__global__ __launch_bounds__(256) void conv_f32_f16(const float* __restrict__ src,
                                                    f16* __restrict__ dst, long n) {
  long i = ((long)blockIdx.x * 256 + threadIdx.x) * 8;
  if (i + 8 <= n) {
    float4 a = *(const float4*)(src + i);
    float4 b = *(const float4*)(src + i + 4);
    f16x8 o = {(f16)a.x, (f16)a.y, (f16)a.z, (f16)a.w,
               (f16)b.x, (f16)b.y, (f16)b.z, (f16)b.w};
    *(f16x8*)(dst + i) = o;
  }
}

// ---------------- batched weight conversion (12 tensors) ----------------
struct ConvArgs { const float* s[12]; f16* d[12]; long n[12]; };
__global__ __launch_bounds__(256) void conv_many(ConvArgs a) {
  int t = blockIdx.y;
  long i = ((long)blockIdx.x * 256 + threadIdx.x) * 8;
  if (i + 8 <= a.n[t]) {
    const float* src = a.s[t];
    float4 x = *(const float4*)(src + i);
    float4 y = *(const float4*)(src + i + 4);
    f16x8 o = {(f16)x.x, (f16)x.y, (f16)x.z, (f16)x.w,
               (f16)y.x, (f16)y.y, (f16)y.z, (f16)y.w};
    *(f16x8*)(a.d[t] + i) = o;
  }
}

// ---------------- batched 1024x1024 transpose f32->f16 (Wv -> WvT) ----------------
struct TpArgs { const float* s[3]; f16* d[3]; };
__global__ __launch_bounds__(256) void transpose3(TpArgs a) {
  __shared__ float t[32][33];
  int h = blockIdx.z;
  int bx = blockIdx.x * 32, by = blockIdx.y * 32;
  int tx = threadIdx.x & 31, ty = threadIdx.x >> 5;
  const float* src = a.s[h];
  f16* dst = a.d[h];
  #pragma unroll
  for (int r = 0; r < 32; r += 8)
    t[ty + r][tx] = src[(long)(by + ty + r) * 1024 + bx + tx];
  __syncthreads();
  #pragma unroll
  for (int r = 0; r < 32; r += 8)
    dst[(long)(bx + ty + r) * 1024 + by + tx] = (f16)t[tx][ty + r];
}

// ---------------- bvo = Wo @ bv + bo (batched over heads) ----------------
struct BvoArgs { const float* Wo[3]; const float* bv[3]; const float* bo[3]; float* out[3]; };
__global__ __launch_bounds__(64) void make_bvo3(BvoArgs a) {
  int h = blockIdx.y, r = blockIdx.x, l = threadIdx.x;
  const float* Wo = a.Wo[h];
  const float* bv = a.bv[h];
  float s = 0.0f;
  for (int k = l; k < 1024; k += 64) s += Wo[(long)r * 1024 + k] * bv[k];
  #pragma unroll
  for (int off = 32; off > 0; off >>= 1) s += __shfl_xor(s, off);
  if (l == 0) a.out[h][r] = s + a.bo[h][r];
}

__device__ __forceinline__ float2 block_reduce2(float a, float b) {
  #pragma unroll
  for (int off = 32; off > 0; off >>= 1) {
    a += __shfl_xor(a, off);
    b += __shfl_xor(b, off);
  }
  __shared__ float2 red[4];
  int wv = threadIdx.x >> 6;
  if ((threadIdx.x & 63) == 0) red[wv] = make_float2(a, b);
  __syncthreads();
  float2 r0 = red[0], r1 = red[1], r2 = red[2], r3 = red[3];
  return make_float2(r0.x + r1.x + r2.x + r3.x, r0.y + r1.y + r2.y + r3.y);
}

// ---------------- merged = [rmsnorm(h_prev), rmsnorm(tok)] ----------------
__global__ __launch_bounds__(256) void merge_rms(const float* __restrict__ hprev,
                                                 const float* __restrict__ embed,
                                                 const int* __restrict__ tok,
                                                 f16* __restrict__ merged, int koff,
                                                 int hsel) {
  int r = blockIdx.x;
  int b = r / NPOS, t = r - b * NPOS;
  int tid = threadIdx.x;
  const float* hrow = (hsel >= 0)
      ? embed + (long)tok[b * 512 + t + hsel] * DMODEL
      : hprev + (long)r * DMODEL;
  float4 hv = ((const float4*)hrow)[tid];
  float4 tv = ((const float4*)(embed + (long)tok[b * 512 + t + koff] * DMODEL))[tid];
  float sh = hv.x * hv.x + hv.y * hv.y + hv.z * hv.z + hv.w * hv.w;
  float st = tv.x * tv.x + tv.y * tv.y + tv.z * tv.z + tv.w * tv.w;
  float2 tot = block_reduce2(sh, st);
  float ih = 1.0f / sqrtf(tot.x * (1.0f / DMODEL) + 1e-8f);
  float it = 1.0f / sqrtf(tot.y * (1.0f / DMODEL) + 1e-8f);
  f16x4 oh = {(f16)(hv.x * ih), (f16)(hv.y * ih), (f16)(hv.z * ih), (f16)(hv.w * ih)};
  f16x4 ot = {(f16)(tv.x * it), (f16)(tv.y * it), (f16)(tv.z * it), (f16)(tv.w * it)};
  *(f16x4*)(merged + (long)r * 2048 + tid * 4) = oh;
  *(f16x4*)(merged + (long)r * 2048 + 1024 + tid * 4) = ot;
}

// ---------------- y = LN(x + res) * g + b ----------------
__global__ __launch_bounds__(256) void add_ln(const float* __restrict__ x,
                                              const float* __restrict__ res,
                                              const float* __restrict__ g,
                                              const float* __restrict__ bb,
                                              float* __restrict__ yf,
                                              f16* __restrict__ yh) {
  int r = blockIdx.x, tid = threadIdx.x;
  float4 a = ((const float4*)(x + (long)r * DMODEL))[tid];
  float4 c = ((const float4*)(res + (long)r * DMODEL))[tid];
  a.x += c.x; a.y += c.y; a.z += c.z; a.w += c.w;
  float s  = a.x + a.y + a.z + a.w;
  float ss = a.x * a.x + a.y * a.y + a.z * a.z + a.w * a.w;
  float2 tot = block_reduce2(s, ss);
  float mean = tot.x * (1.0f / DMODEL);
  float var  = tot.y * (1.0f / DMODEL) - mean * mean;
  float inv  = 1.0f / sqrtf(var + 1e-5f);
  float4 gv = ((const float4*)g)[tid];
  float4 bv = ((const float4*)bb)[tid];
  float y0 = (a.x - mean) * inv * gv.x + bv.x;
  float y1 = (a.y - mean) * inv * gv.y + bv.y;
  float y2 = (a.z - mean) * inv * gv.z + bv.z;
  float y3 = (a.w - mean) * inv * gv.w + bv.w;
  float4 o = {y0, y1, y2, y3};
  ((float4*)(yf + (long)r * DMODEL))[tid] = o;
  f16x4 oh = {(f16)y0, (f16)y1, (f16)y2, (f16)y3};
  *(f16x4*)(yh + (long)r * DMODEL + tid * 4) = oh;
}

// ---------------- small GEMM: 64x64 tile, 3-buffer depth-2 prefetch ----------------
template <int HAS_BIAS, int RELU, int WF32, int WF16, int MASK>
__global__ __launch_bounds__(256) void gemm_sm(const f16* __restrict__ A,
                                               const f16* __restrict__ B,
                                               const float* __restrict__ bias,
                                               float* __restrict__ Cf,
                                               f16* __restrict__ Ch,
                                               int K, int N, long ldc, long coff,
                                               int mval, long zsA, long zsB, long zsC) {
  __shared__ __align__(16) f16 sA[3][2048];
  __shared__ __align__(16) f16 sB[3][2048];
  const int tid  = threadIdx.x;
  const int lane = tid & 63, wv = tid >> 6;
  const int wm = wv >> 1, wn = wv & 1;
  const int bm = blockIdx.y, bn = blockIdx.x;
  const int lr = lane & 15, lk = lane >> 4;

  A += (long)blockIdx.z * zsA;
  B += (long)blockIdx.z * zsB;
  Ch += (long)blockIdx.z * zsC;

  const f16* gA = A + ((long)(bm * 64 + (tid >> 2))) * K + (tid & 3) * 8;
  const f16* gB = B + ((long)(bn * 64 + (tid >> 2))) * K + (tid & 3) * 8;

  const int aoff = (wm * 32 + lr) * 32 + lk * 8;
  const int boff = (wn * 32 + lr) * 32 + lk * 8;

  f32x4 acc[2][2] = {};

#define SSTAGE(buf, kt)                                \
  gld_lds16(gA + (long)(kt) * 32, &sA[buf][tid * 8]);  \
  gld_lds16(gB + (long)(kt) * 32, &sB[buf][tid * 8]);

  const int nk = K >> 5;
  SSTAGE(0, 0);
  SSTAGE(1, 1);

  int cur = 0, stg = 2;
  for (int kt = 0; kt < nk; ++kt) {
    if (kt + 1 < nk) { VM2; } else { VM0; }
    BAR;
    if (kt + 2 < nk) { SSTAGE(stg, kt + 2); }
    f16x8 af0 = *(const f16x8*)&sA[cur][aoff];
    f16x8 af1 = *(const f16x8*)&sA[cur][aoff + 512];
    f16x8 bf0 = *(const f16x8*)&sB[cur][boff];
    f16x8 bf1 = *(const f16x8*)&sB[cur][boff + 512];
    acc[0][0] = MFMA16(af0, bf0, acc[0][0]);
    acc[0][1] = MFMA16(af0, bf1, acc[0][1]);
    acc[1][0] = MFMA16(af1, bf0, acc[1][0]);
    acc[1][1] = MFMA16(af1, bf1, acc[1][1]);
    cur = cur == 2 ? 0 : cur + 1;
    stg = stg == 2 ? 0 : stg + 1;
  }
#undef SSTAGE

  const int row0 = bm * 64 + wm * 32 + lk * 4;
  const int col0 = bn * 64 + wn * 32 + lr;
  #pragma unroll
  for (int mi = 0; mi < 2; ++mi) {
    #pragma unroll
    for (int ni = 0; ni < 2; ++ni) {
      int col = col0 + ni * 16;
      float bs = HAS_BIAS ? bias[col] : 0.0f;
      #pragma unroll
      for (int rg = 0; rg < 4; ++rg) {
        int row = row0 + mi * 16 + rg;
        if (!MASK || row < mval) {
          float v = acc[mi][ni][rg] + bs;
          if (RELU) v = v > 0.0f ? v : 0.0f;
          if (WF32) Cf[(long)row * ldc + coff + col] = v;
          if (WF16) Ch[(long)row * N + col] = (f16)v;
        }
      }
    }
  }
}

// ---------------- mega logits GEMM: M=6144 (3 heads), 256x256 tile ----------------
// BK=64, 2 dbuf, K-half staging [buf][kh][256x32]. 4 phases/K-tile, each:
//   {ds_read subtile + stage 1 half (pre-barrier) -> BAR -> lgkmcnt(0) +
//    sched_barrier(0) -> setprio(1) 16xMFMA setprio(0) -> BAR}.
// Counted waits, per-wave ledger (each STAGE = 2 loads):
//   outstanding at P2/P4 pre-wait = 8; vmcnt(4) retires exactly the 2 halves
//   the next 2 phases read; following BAR publishes cross-wave. Prologue
//   stages tile0 (8 loads) + vmcnt(4) + BAR. Second barrier per phase proves
//   all waves' reads of a buffer completed before it is restaged (anti-
//   overwrite). Wrap-stage at t=nt-1 keeps the ledger uniform; VM0 drains.
// LDS chunk-XOR swizzle (verified 0 conflicts): lane-constant on reads,
// folded into source pointer for linear-dest gld_lds.
__global__ __launch_bounds__(512, 2) void gemm256x(const f16* __restrict__ A,
                                                   const f16* __restrict__ B,
                                                   float* __restrict__ C) {
  __shared__ __align__(16) f16 sA[2][2][8192];
  __shared__ __align__(16) f16 sB[2][2][8192];
  const int K = 1024;
  const int tid = threadIdx.x;
  const int lane = tid & 63;
  const int wv = tid >> 6;
  const int wm = wv >> 2, wn = wv & 3;
  const int lr = lane & 15, lk = lane >> 4;

  // A-resident XCD swizzle: 3000 blocks = 8 XCDs x 375; each XCD owns 3 bm.
  const int flat = blockIdx.y * 125 + blockIdx.x;
  const int xcd = flat & 7, idx = flat >> 3;
  const int bm = xcd * 3 + (idx % 3);
  const int bn = idx / 3;

  const int srow = tid >> 2;                         // 0..127
  const int schunk = (tid & 3) ^ ((tid >> 3) & 3);   // pre-swizzled source chunk
  const f16* gA = A + (long)(bm * 256 + srow) * K + schunk * 8;
  const f16* gB = B + (long)(bn * 256 + srow) * K + schunk * 8;
  const long rstep = 128L * (long)K;

  const int swz = ((lr >> 1) & 3) << 3;              // elem-XOR for frag reads
  const int aoff = (((wm * 128 + lr) * 32) + lk * 8) ^ swz;  // + mi*512
  const int boff = (((wn * 64  + lr) * 32) + lk * 8) ^ swz;  // + ni*512

  f32x4 acc[8][4] = {};

#define STG_A(s, h, ko)                                                  \
  gld_lds16(gA + (ko) + (h) * 32, &sA[s][h][tid * 8]);                   \
  gld_lds16(gA + (ko) + (h) * 32 + rstep, &sA[s][h][tid * 8 + 4096]);
#define STG_B(s, h, ko)                                                  \
  gld_lds16(gB + (ko) + (h) * 32, &sB[s][h][tid * 8]);                   \
  gld_lds16(gB + (ko) + (h) * 32 + rstep, &sB[s][h][tid * 8 + 4096]);

  // prologue: tile 0 (halves in stage order Ak0,Bk0,Ak1,Bk1), publish kh0
  STG_A(0, 0, 0); STG_B(0, 0, 0); STG_A(0, 1, 0); STG_B(0, 1, 0);
  VM4;   // retires Ak0,Bk0 of tile 0
  BAR;

  const int nt = 16;  // K / 64
  for (int t = 0; t < nt; ++t) {
    const int cur = t & 1, nxt = cur ^ 1;
    const long kn = (long)((t + 1 < nt) ? (t + 1) : 0) * 64;
    f16x8 alo[4], ahi[4], bf[4];

    // ---- P1: kh0, mi 0-3 ----
    #pragma unroll
    for (int i = 0; i < 4; ++i) alo[i] = *(const f16x8*)&sA[cur][0][aoff + i * 512];
    #pragma unroll
    for (int j = 0; j < 4; ++j) bf[j] = *(const f16x8*)&sB[cur][0][boff + j * 512];
    STG_A(nxt, 0, kn);
    BAR; LGKM0; SCHED0;
    __builtin_amdgcn_s_setprio(1);
    #pragma unroll
    for (int i = 0; i < 4; ++i)
      #pragma unroll
      for (int j = 0; j < 4; ++j)
        acc[i][j] = MFMA16(alo[i], bf[j], acc[i][j]);
    __builtin_amdgcn_s_setprio(0);
    BAR;

    // ---- P2: kh0, mi 4-7 ----
    #pragma unroll
    for (int i = 0; i < 4; ++i) ahi[i] = *(const f16x8*)&sA[cur][0][aoff + (i + 4) * 512];
    STG_B(nxt, 0, kn);
    VM4;   // retires Ak1,Bk1 of tile t -> next BAR publishes kh1
    BAR; LGKM0; SCHED0;
    __builtin_amdgcn_s_setprio(1);
    #pragma unroll
    for (int i = 0; i < 4; ++i)
      #pragma unroll
      for (int j = 0; j < 4; ++j)
        acc[i + 4][j] = MFMA16(ahi[i], bf[j], acc[i + 4][j]);
    __builtin_amdgcn_s_setprio(0);
    BAR;

    // ---- P3: kh1, mi 0-3 ----
    #pragma unroll
    for (int i = 0; i < 4; ++i) alo[i] = *(const f16x8*)&sA[cur][1][aoff + i * 512];
    #pragma unroll
    for (int j = 0; j < 4; ++j) bf[j] = *(const f16x8*)&sB[cur][1][boff + j * 512];
    STG_A(nxt, 1, kn);
    BAR; LGKM0; SCHED0;
    __builtin_amdgcn_s_setprio(1);
    #pragma unroll
    for (int i = 0; i < 4; ++i)
      #pragma unroll
      for (int j = 0; j < 4; ++j)
        acc[i][j] = MFMA16(alo[i], bf[j], acc[i][j]);
    __builtin_amdgcn_s_setprio(0);
    BAR;

    // ---- P4: kh1, mi 4-7 ----
    #pragma unroll
    for (int i = 0; i < 4; ++i) ahi[i] = *(const f16x8*)&sA[cur][1][aoff + (i + 4) * 512];
    STG_B(nxt, 1, kn);
    VM4;   // retires Ak0,Bk0 of tile t+1 -> next BAR publishes its kh0
    BAR; LGKM0; SCHED0;
    __builtin_amdgcn_s_setprio(1);
    #pragma unroll
    for (int i = 0; i < 4; ++i)
      #pragma unroll
      for (int j = 0; j < 4; ++j)
        acc[i + 4][j] = MFMA16(ahi[i], bf[j], acc[i + 4][j]);
    __builtin_amdgcn_s_setprio(0);
    BAR;
  }
  VM0;  // drain wrap stages

  // epilogue: head = bm>>3 (blocks never straddle heads); plain f32 stores
  const int head = bm >> 3;
  const long coff = (long)head * 32000;
  const int row0 = (bm & 7) * 256 + wm * 128 + lk * 4;
  const int col0 = bn * 256 + wn * 64 + lr;
  #pragma unroll
  for (int mi = 0; mi < 8; ++mi) {
    #pragma unroll
    for (int ni = 0; ni < 4; ++ni) {
      int col = col0 + ni * 16;
      #pragma unroll
      for (int rg = 0; rg < 4; ++rg) {
        int row = row0 + mi * 16 + rg;
        if (row < MROWS) C[(long)row * 96000 + coff + col] = acc[mi][ni][rg];
      }
    }
  }
#undef STG_A
#undef STG_B
}

// ---------------- host-side orchestration ----------------
extern "C" void kernel_launch(void* const* d_in, const int* in_sizes, int n_in,
                              void* d_out, int out_size, void* d_ws, size_t ws_size,
                              hipStream_t stream) {
  const int*   tok   = (const int*)d_in[0];
  const float* embed = (const float*)d_in[1];
  auto P = [&](int k, int j) { return (const float*)d_in[2 + k * 14 + j]; };
  float* out = (float*)d_out;

  char* w = (char*)d_ws;
  auto alloc = [&](size_t bytes) { char* p = w; w += bytes; return p; };
  const size_t MM = (size_t)1024 * 1024;

  f16* embed_h = (f16*)alloc((size_t)32000 * 1024 * 2);
  f16* Wo_all  = (f16*)alloc(3 * MM * 2);
  f16* Wvo_all = (f16*)alloc(3 * MM * 2);
  f16 *Wm_h[3], *W1_h[3], *W2_h[3];
  for (int k = 0; k < 3; ++k) {
    Wm_h[k]  = (f16*)alloc((size_t)1024 * 2048 * 2);
    W1_h[k]  = (f16*)alloc((size_t)2048 * 1024 * 2);
    W2_h[k]  = (f16*)alloc((size_t)1024 * 2048 * 2);
  }
  float* hprev  = (float*)alloc((size_t)MPAD * 1024 * 4);
  f16*   h_all  = (f16*)alloc((size_t)3 * MPAD * 1024 * 2);
  f16*   merged = (f16*)alloc((size_t)MPAD * 2048 * 2);
  float* xf     = (float*)alloc((size_t)MPAD * 1024 * 4);
  f16*   xh     = (f16*)alloc((size_t)MPAD * 1024 * 2);
  f16*   ff1    = (f16*)alloc((size_t)MPAD * 2048 * 2);
  float* t1     = (float*)alloc((size_t)MPAD * 1024 * 4);
  float* bvo    = (float*)alloc(3 * 1024 * 4);
  f16* WvT_all = merged;  // scratch overlay (merged written later, stream-ordered)

  // ---- prep ----
  conv_f32_f16<<<16000, 256, 0, stream>>>(embed, embed_h, (long)32000 * 1024);

  ConvArgs ca;
  for (int k = 0; k < 3; ++k) {
    ca.s[k*4+0] = P(k, 0); ca.d[k*4+0] = Wm_h[k];        ca.n[k*4+0] = (long)1024 * 2048;
    ca.s[k*4+1] = P(k, 4); ca.d[k*4+1] = Wo_all + k*MM;  ca.n[k*4+1] = (long)1024 * 1024;
    ca.s[k*4+2] = P(k, 6); ca.d[k*4+2] = W1_h[k];        ca.n[k*4+2] = (long)2048 * 1024;
    ca.s[k*4+3] = P(k, 8); ca.d[k*4+3] = W2_h[k];        ca.n[k*4+3] = (long)1024 * 2048;
  }
  conv_many<<<dim3(1024, 12), 256, 0, stream>>>(ca);

  TpArgs ta;
  for (int k = 0; k < 3; ++k) { ta.s[k] = P(k, 2); ta.d[k] = WvT_all + k * MM; }
  transpose3<<<dim3(32, 32, 3), 256, 0, stream>>>(ta);

  gemm_sm<0, 0, 0, 1, 0><<<dim3(16, 16, 3), 256, 0, stream>>>(
      Wo_all, WvT_all, nullptr, nullptr, Wvo_all, 1024, 1024, 1024L, 0L, 1024,
      (long)MM, (long)MM, (long)MM);

  BvoArgs ba;
  for (int k = 0; k < 3; ++k) {
    ba.Wo[k] = P(k, 4); ba.bv[k] = P(k, 3); ba.bo[k] = P(k, 5); ba.out[k] = bvo + k * 1024;
  }
  make_bvo3<<<dim3(1024, 3), 64, 0, stream>>>(ba);

  // ---- 3 encoder chains (logits deferred to one mega GEMM) ----
  for (int k = 0; k < 3; ++k) {
    merge_rms<<<MROWS, 256, 0, stream>>>(hprev, embed, tok, merged, k + 1,
                                         k == 0 ? 0 : -1);
    gemm_sm<1, 0, 1, 1, 0><<<dim3(16, 32), 256, 0, stream>>>(
        merged, Wm_h[k], P(k, 1), xf, xh, 2048, 1024, 1024L, 0L, MROWS, 0L, 0L, 0L);
    gemm_sm<1, 0, 1, 0, 0><<<dim3(16, 32), 256, 0, stream>>>(
        xh, Wvo_all + k * MM, bvo + k * 1024, t1, nullptr, 1024, 1024, 1024L, 0L,
        MROWS, 0L, 0L, 0L);
    add_ln<<<MROWS, 256, 0, stream>>>(xf, t1, P(k, 10), P(k, 11), xf, xh);
    gemm_sm<1, 1, 0, 1, 0><<<dim3(32, 32), 256, 0, stream>>>(
        xh, W1_h[k], P(k, 7), nullptr, ff1, 1024, 2048, 2048L, 0L, MROWS, 0L, 0L, 0L);
    gemm_sm<1, 0, 1, 0, 0><<<dim3(16, 32), 256, 0, stream>>>(
        ff1, W2_h[k], P(k, 9), t1, nullptr, 2048, 1024, 1024L, 0L, MROWS, 0L, 0L, 0L);
    add_ln<<<MROWS, 256, 0, stream>>>(xf, t1, P(k, 12), P(k, 13), hprev,
                                      h_all + (size_t)k * MPAD * 1024);
  }

  // ---- one mega logits GEMM ----
  gemm256x<<<dim3(125, 24), 512, 0, stream>>>(h_all, embed_h, out);
}